// Round 1
// baseline (42601.627 us; speedup 1.0000x reference)
//
#include <hip/hip_runtime.h>

// ---------------- problem constants ----------------
#define B_   32
#define S_   512
#define E_   768
#define H_   1024
#define G4_  4096          // 4*H
#define BS_  16384         // B*S
#define NWG_ 256           // workgroups in cooperative recurrence

// ---------------- helpers ----------------
__device__ __forceinline__ unsigned short f2b(float f) {
    union { float f; unsigned u; } a; a.f = f;
    unsigned r = a.u + 0x7FFFu + ((a.u >> 16) & 1u);   // round-to-nearest-even
    return (unsigned short)(r >> 16);
}
__device__ __forceinline__ float b2f(unsigned short u) {
    union { unsigned u; float f; } a; a.u = ((unsigned)u) << 16;
    return a.f;
}

typedef __attribute__((ext_vector_type(8))) short bh8;   // 8 x bf16 (4 VGPRs)
typedef __attribute__((ext_vector_type(4))) float f4x;   // MFMA f32 accumulator

// ---------------- mask dtype detection ----------------
// emotion_mask is a jax bool (V,) -- harness may pass int32 (0/1) or packed
// 1-byte bools. Packed bytes -> some of the first 256 u32 words exceed 1.
__global__ void detect_mask_k(const unsigned* __restrict__ m, unsigned* __restrict__ flag) {
    int t = threadIdx.x;                 // 64 threads
    unsigned bad = 0;
#pragma unroll
    for (int i = 0; i < 4; ++i) { unsigned v = m[t * 4 + i]; bad |= (v > 1u); }
    unsigned long long bb = __ballot(bad != 0u);
    if (t == 0) flag[0] = (bb != 0ull) ? 1u : 0u;
}

// ---------------- blend: hdn = where(emo & s>=1, (emb+hid)*0.5, hid), bf16 out ----------------
__global__ void blend_k(const int* __restrict__ x, const void* __restrict__ mask,
                        const float* __restrict__ hid, const float* __restrict__ emb,
                        const unsigned* __restrict__ flag, unsigned short* __restrict__ hdn) {
    int row = blockIdx.x;                // b*512 + s
    int t = threadIdx.x;                 // 192 threads, 4 floats each (768)
    if (t >= 192) return;
    int s = row & 511;
    int tok = x[row];
    bool emo;
    if (flag[0]) emo = ((const unsigned char*)mask)[tok] != 0;
    else         emo = ((const int*)mask)[tok] != 0;
    bool bl = emo && (s >= 1);
    float4 v = *(const float4*)(hid + (size_t)row * E_ + t * 4);
    if (bl) {
        float4 e = *(const float4*)(emb + (size_t)tok * E_ + t * 4);
        v.x = (v.x + e.x) * 0.5f; v.y = (v.y + e.y) * 0.5f;
        v.z = (v.z + e.z) * 0.5f; v.w = (v.w + e.w) * 0.5f;
    }
    ushort4 o; o.x = f2b(v.x); o.y = f2b(v.y); o.z = f2b(v.z); o.w = f2b(v.w);
    *(ushort4*)(hdn + (size_t)row * E_ + t * 4) = o;
}

// ---------------- f32 -> bf16 weight conversion ----------------
__global__ void cvt_k(const float* __restrict__ in, unsigned short* __restrict__ o, int n) {
    int i = (blockIdx.x * blockDim.x + threadIdx.x) * 4;
    if (i >= n) return;
    float4 v = *(const float4*)(in + i);
    ushort4 u; u.x = f2b(v.x); u.y = f2b(v.y); u.z = f2b(v.z); u.w = f2b(v.w);
    *(ushort4*)(o + i) = u;
}

// ---------------- bf16 MFMA GEMM:  C[M,N] = A[M,K] @ B[N,K]^T  ----------------
// 128x128 tile, BK=64, 4 waves each 64x64 (4x4 frags of 16x16x32).
// XOR swizzle ((row&7)<<4) on 128B LDS rows -> 2-way (free) bank aliasing.
// AF32: A operand is fp32 in global, converted to bf16 during staging.
template <int AF32>
__global__ __launch_bounds__(256) void gemm_k(const void* __restrict__ Ap,
        const unsigned short* __restrict__ Bp, unsigned short* __restrict__ Cp,
        int K, int Nreal, int ldc, const float* __restrict__ bias, int act) {
    __shared__ char smA[16384];
    __shared__ char smB[16384];
    const int tid = threadIdx.x, l = tid & 63, w = tid >> 6;
    const int m0 = blockIdx.x * 128, n0 = blockIdx.y * 128;
    const int wr = (w >> 1) * 64, wc = (w & 1) * 64;
    f4x acc[4][4] = {};
    for (int k0 = 0; k0 < K; k0 += 64) {
#pragma unroll
        for (int it = 0; it < 4; ++it) {
            int idx = it * 256 + tid;            // 0..1023 : 128 rows x 8 x 16B
            int row = idx >> 3, c16 = idx & 7;
            int sof = (row * 128 + c16 * 16) ^ ((row & 7) << 4);
            bh8 va;
            if (AF32) {
                const float* ap = (const float*)Ap + (size_t)(m0 + row) * K + k0 + c16 * 8;
                float4 f0 = *(const float4*)ap;
                float4 f1 = *(const float4*)(ap + 4);
                va[0] = (short)f2b(f0.x); va[1] = (short)f2b(f0.y);
                va[2] = (short)f2b(f0.z); va[3] = (short)f2b(f0.w);
                va[4] = (short)f2b(f1.x); va[5] = (short)f2b(f1.y);
                va[6] = (short)f2b(f1.z); va[7] = (short)f2b(f1.w);
            } else {
                va = *(const bh8*)((const unsigned short*)Ap + (size_t)(m0 + row) * K + k0 + c16 * 8);
            }
            *(bh8*)(smA + sof) = va;
            int nr = n0 + row;
            bh8 vb = {0, 0, 0, 0, 0, 0, 0, 0};
            if (nr < Nreal) vb = *(const bh8*)(Bp + (size_t)nr * K + k0 + c16 * 8);
            *(bh8*)(smB + sof) = vb;
        }
        __syncthreads();
#pragma unroll
        for (int kk = 0; kk < 2; ++kk) {
            bh8 af[4], bf8[4];
#pragma unroll
            for (int f = 0; f < 4; ++f) {
                int ra = wr + f * 16 + (l & 15);
                af[f] = *(const bh8*)(smA + ((ra * 128 + kk * 64 + ((l >> 4) << 4)) ^ ((ra & 7) << 4)));
                int rb = wc + f * 16 + (l & 15);
                bf8[f] = *(const bh8*)(smB + ((rb * 128 + kk * 64 + ((l >> 4) << 4)) ^ ((rb & 7) << 4)));
            }
#pragma unroll
            for (int fi = 0; fi < 4; ++fi)
#pragma unroll
                for (int fj = 0; fj < 4; ++fj)
                    acc[fi][fj] = __builtin_amdgcn_mfma_f32_16x16x32_bf16(af[fi], bf8[fj], acc[fi][fj], 0, 0, 0);
        }
        __syncthreads();
    }
    // epilogue: C/D layout (verified): col = lane&15, row = (lane>>4)*4 + reg
#pragma unroll
    for (int fi = 0; fi < 4; ++fi) {
        int rb2 = wr + fi * 16 + ((l >> 4) << 2);
#pragma unroll
        for (int fj = 0; fj < 4; ++fj) {
            int cc = n0 + wc + fj * 16 + (l & 15);
            if (cc < Nreal) {
                float bv = bias ? bias[cc] : 0.f;
#pragma unroll
                for (int i = 0; i < 4; ++i) {
                    float xv = acc[fi][fj][i] + bv;
                    if (act) xv = tanhf(xv);
                    Cp[(size_t)(m0 + rb2 + i) * ldc + cc] = f2b(xv);
                }
            }
        }
    }
}

// ---------------- persistent cooperative LSTM recurrence (one layer) ----------------
// 256 WGs x 256 thr. WG owns 4 hidden units = 16 gate rows (i,f,g,o x 4 units),
// Whh slice (32KB bf16) LDS-resident across all 512 steps. Per step:
//   gates[32 batch][16 rows] = h_prev @ Whh_sliceT  (MFMA, K=1024 split over 4 waves)
//   + G[b,t,row] + bias ; LSTM cell elementwise ; h_next bf16 to global ;
//   two-level atomic grid barrier (monotonic generation counter).
__global__ __launch_bounds__(256) void recur_k(const unsigned short* __restrict__ G,
        const unsigned short* __restrict__ Whh, const float* __restrict__ bih,
        const float* __restrict__ bhh, unsigned short* outb, float* outf,
        unsigned short* he, unsigned short* ho, unsigned* bar) {
    const int wg = blockIdx.x, tid = threadIdx.x, l = tid & 63, wv = tid >> 6;
    __shared__ char  whh_s[32768];                 // 16 rows x 1024 bf16, swizzled
    __shared__ float red_s[4][2][16][16];          // per-wave K-partials
    __shared__ float gates_s[32][16];
    __shared__ float c_s[128];                     // fp32 cell state [b][u]
    __shared__ float bias_s[16];
    // load Whh slice: row n -> global gate row (n>>2)*1024 + wg*4 + (n&3)
#pragma unroll
    for (int it = 0; it < 8; ++it) {
        int idx = it * 256 + tid;                  // 0..2047 : 16 rows x 128 x 16B
        int row = idx >> 7, c16 = idx & 127;
        int Rg = ((row >> 2) << 10) + (wg << 2) + (row & 3);
        bh8 v = *(const bh8*)(Whh + (size_t)Rg * H_ + c16 * 8);
        *(bh8*)(whh_s + ((row * 2048 + c16 * 16) ^ ((row & 7) << 4))) = v;
    }
    if (tid < 16) {
        int Rg = ((tid >> 2) << 10) + (wg << 2) + (tid & 3);
        bias_s[tid] = bih[Rg] + bhh[Rg];
    }
    if (tid < 128) c_s[tid] = 0.f;
    __syncthreads();

    for (int t = 0; t < S_; ++t) {
        const unsigned short* hp = (t & 1) ? ho : he;
        unsigned short* hn = (t & 1) ? he : ho;
        // MFMA phase: wave wv handles K in [wv*256, wv*256+256)
        f4x a0 = {0.f, 0.f, 0.f, 0.f}, a1v = {0.f, 0.f, 0.f, 0.f};
        const int kch = (l >> 4) << 4;             // byte offset of k-subgroup
#pragma unroll
        for (int s = 0; s < 8; ++s) {
            int kb = (wv * 256 + s * 32) * 2 + kch;
            bh8 x0 = *(const bh8*)((const char*)hp + (l & 15) * 2048 + kb);
            bh8 x1 = *(const bh8*)((const char*)hp + (16 + (l & 15)) * 2048 + kb);
            bh8 wq = *(const bh8*)(whh_s + (((l & 15) * 2048 + kb) ^ (((l & 15) & 7) << 4)));
            a0  = __builtin_amdgcn_mfma_f32_16x16x32_bf16(x0, wq, a0, 0, 0, 0);
            a1v = __builtin_amdgcn_mfma_f32_16x16x32_bf16(x1, wq, a1v, 0, 0, 0);
        }
#pragma unroll
        for (int i = 0; i < 4; ++i) {
            red_s[wv][0][((l >> 4) << 2) + i][l & 15] = a0[i];
            red_s[wv][1][((l >> 4) << 2) + i][l & 15] = a1v[i];
        }
        __syncthreads();
        // reduce K-partials + G + bias
#pragma unroll
        for (int q = 0; q < 2; ++q) {
            int idx = tid * 2 + q, b = idx >> 4, n = idx & 15;
            float g = red_s[0][b >> 4][b & 15][n] + red_s[1][b >> 4][b & 15][n]
                    + red_s[2][b >> 4][b & 15][n] + red_s[3][b >> 4][b & 15][n];
            int Rg = ((n >> 2) << 10) + (wg << 2) + (n & 3);
            g += b2f(G[((size_t)b * S_ + t) * G4_ + Rg]) + bias_s[n];
            gates_s[b][n] = g;
        }
        __syncthreads();
        if (tid < 128) {                           // (b,u): b = tid>>2, u = tid&3
            int b = tid >> 2, u = tid & 3;
            float gi = gates_s[b][u],     gf = gates_s[b][4 + u];
            float gg = gates_s[b][8 + u], go = gates_s[b][12 + u];
            float si = 1.f / (1.f + __expf(-gi));
            float sf = 1.f / (1.f + __expf(-gf));
            float so = 1.f / (1.f + __expf(-go));
            float c = sf * c_s[tid] + si * tanhf(gg);
            float hv = so * tanhf(c);
            c_s[tid] = c;
            int col = (wg << 2) + u;
            hn[b * H_ + col] = f2b(hv);
            if (outb) outb[((size_t)b * S_ + t) * H_ + col] = f2b(hv);
            if (outf) outf[((size_t)b * S_ + t) * H_ + col] = hv;
        }
        // ---- grid barrier: publish h, two-level arrive, spin on generation ----
        __threadfence();
        __syncthreads();
        if (tid == 0) {
            unsigned a = __hip_atomic_fetch_add(&bar[wg >> 5], 1u, __ATOMIC_ACQ_REL, __HIP_MEMORY_SCOPE_AGENT);
            if ((a & 31u) == 31u) {
                unsigned r = __hip_atomic_fetch_add(&bar[8], 1u, __ATOMIC_ACQ_REL, __HIP_MEMORY_SCOPE_AGENT);
                if ((r & 7u) == 7u)
                    __hip_atomic_store(&bar[9], (r >> 3) + 1u, __ATOMIC_RELEASE, __HIP_MEMORY_SCOPE_AGENT);
            }
            while (__hip_atomic_load(&bar[9], __ATOMIC_RELAXED, __HIP_MEMORY_SCOPE_AGENT) < (unsigned)(t + 1))
                __builtin_amdgcn_s_sleep(1);
            __threadfence();                       // acquire: invalidate L1/L2 before next h reads
        }
        __syncthreads();
    }
}

// ---------------- attention score:  sc[row] = sum_r a1[row,r]*W2[r]  (b2 cancels in softmax) ----------------
__global__ void score_k(const unsigned short* __restrict__ a1, const float* __restrict__ W2,
                        float* __restrict__ sc) {
    int r = blockIdx.x * blockDim.x + threadIdx.x;   // 0..16383
    const unsigned short* p = a1 + (size_t)r * 128;
    float s = 0.f;
#pragma unroll
    for (int i = 0; i < 100; ++i) s += b2f(p[i]) * W2[i];
    sc[r] = s;
}

// ---------------- per-batch: softmax over S -> w ; sent = sum_s w*out2 ; logits ----------------
__global__ __launch_bounds__(256) void attn_k(const float* __restrict__ sc,
        const float* __restrict__ out2, const float* __restrict__ Wf,
        const float* __restrict__ bf, float* __restrict__ out) {
    int b = blockIdx.x, t = threadIdx.x;
    __shared__ float p[512];
    __shared__ float red[256];
    __shared__ float sent[1024];
    float s0 = sc[b * 512 + t], s1 = sc[b * 512 + 256 + t];
    red[t] = fmaxf(s0, s1);
    __syncthreads();
    for (int o = 128; o > 0; o >>= 1) { if (t < o) red[t] = fmaxf(red[t], red[t + o]); __syncthreads(); }
    float M = red[0];
    __syncthreads();
    float e0 = __expf(s0 - M), e1 = __expf(s1 - M);
    red[t] = e0 + e1;
    __syncthreads();
    for (int o = 128; o > 0; o >>= 1) { if (t < o) red[t] += red[t + o]; __syncthreads(); }
    float inv = 1.f / red[0];
    float w0 = e0 * inv, w1 = e1 * inv;
    p[t] = w0; p[t + 256] = w1;
    out[160 + b * 512 + t] = w0;
    out[160 + b * 512 + 256 + t] = w1;
    __syncthreads();
    float4 acc = {0.f, 0.f, 0.f, 0.f};
    for (int s = 0; s < 512; ++s) {
        float ws = p[s];
        float4 v = *(const float4*)(out2 + ((size_t)b * 512 + s) * H_ + t * 4);
        acc.x += ws * v.x; acc.y += ws * v.y; acc.z += ws * v.z; acc.w += ws * v.w;
    }
    *(float4*)(sent + t * 4) = acc;
    __syncthreads();
    int wv = t >> 6, ln = t & 63;
    for (int n = wv; n < 5; n += 4) {
        float prt = 0.f;
        for (int k = ln; k < 1024; k += 64) prt += sent[k] * Wf[n * 1024 + k];
#pragma unroll
        for (int o = 32; o > 0; o >>= 1) prt += __shfl_down(prt, o);
        if (ln == 0) out[b * 5 + n] = prt + bf[n];
    }
}

// ---------------- workspace layout (bytes) ----------------
#define OFF_FLAG  0u
#define OFF_BAR0  256u
#define OFF_BAR1  512u
#define OFF_H0A   1024u
#define OFF_H0B   (OFF_H0A + 65536u)
#define OFF_H1A   (OFF_H0B + 65536u)
#define OFF_H1B   (OFF_H1A + 65536u)
#define OFF_HDN   263168u                                  // bf16 [16384][768]   25.2MB
#define OFF_W0    (OFF_HDN + (size_t)BS_ * E_ * 2)         // Wih0b  6.3MB
#define OFF_WH0   (OFF_W0 + (size_t)G4_ * E_ * 2)          // Whh0b  8.4MB
#define OFF_W1I   (OFF_WH0 + (size_t)G4_ * H_ * 2)         // Wih1b  8.4MB
#define OFF_WH1   (OFF_W1I + (size_t)G4_ * H_ * 2)         // Whh1b  8.4MB
#define OFF_W1A   (OFF_WH1 + (size_t)G4_ * H_ * 2)         // W1b    0.2MB
#define OFF_G     (OFF_W1A + (size_t)100 * H_ * 2 + 256)   // bf16 [16384][4096] 134MB (reused both layers)
#define OFF_OUT1  (OFF_G + (size_t)BS_ * G4_ * 2)          // bf16 [16384][1024] 33.6MB
#define OFF_OUT2  (OFF_OUT1 + (size_t)BS_ * H_ * 2)        // f32  [16384][1024] 67MB
#define OFF_A1    (OFF_OUT2 + (size_t)BS_ * H_ * 4)        // bf16 [16384][128]   4.2MB
#define OFF_SC    (OFF_A1 + (size_t)BS_ * 128 * 2)         // f32  [16384]

extern "C" void kernel_launch(void* const* d_in, const int* in_sizes, int n_in,
                              void* d_out, int out_size, void* d_ws, size_t ws_size,
                              hipStream_t stream) {
    const int*   x    = (const int*)d_in[0];
    const void*  mask = d_in[1];
    const float* hid  = (const float*)d_in[2];
    const float* emb  = (const float*)d_in[3];
    const float* Wih0 = (const float*)d_in[4];
    const float* Whh0 = (const float*)d_in[5];
    const float* bih0 = (const float*)d_in[6];
    const float* bhh0 = (const float*)d_in[7];
    const float* Wih1 = (const float*)d_in[8];
    const float* Whh1 = (const float*)d_in[9];
    const float* bih1 = (const float*)d_in[10];
    const float* bhh1 = (const float*)d_in[11];
    const float* W1   = (const float*)d_in[12];
    const float* b1   = (const float*)d_in[13];
    const float* W2   = (const float*)d_in[14];
    const float* Wf   = (const float*)d_in[16];
    const float* bfp  = (const float*)d_in[17];
    float* out = (float*)d_out;
    char* ws = (char*)d_ws;

    unsigned*       flag  = (unsigned*)(ws + OFF_FLAG);
    unsigned*       bar0  = (unsigned*)(ws + OFF_BAR0);
    unsigned*       bar1  = (unsigned*)(ws + OFF_BAR1);
    unsigned short* h0a   = (unsigned short*)(ws + OFF_H0A);
    unsigned short* h0b   = (unsigned short*)(ws + OFF_H0B);
    unsigned short* h1a   = (unsigned short*)(ws + OFF_H1A);
    unsigned short* h1b   = (unsigned short*)(ws + OFF_H1B);
    unsigned short* hdn   = (unsigned short*)(ws + OFF_HDN);
    unsigned short* w0b   = (unsigned short*)(ws + OFF_W0);
    unsigned short* wh0b  = (unsigned short*)(ws + OFF_WH0);
    unsigned short* w1ib  = (unsigned short*)(ws + OFF_W1I);
    unsigned short* wh1b  = (unsigned short*)(ws + OFF_WH1);
    unsigned short* w1ab  = (unsigned short*)(ws + OFF_W1A);
    unsigned short* Gb    = (unsigned short*)(ws + OFF_G);
    unsigned short* out1b = (unsigned short*)(ws + OFF_OUT1);
    float*          out2f = (float*)(ws + OFF_OUT2);
    unsigned short* a1b   = (unsigned short*)(ws + OFF_A1);
    float*          scb   = (float*)(ws + OFF_SC);

    // zero: flag + barriers + initial h buffers (ws re-poisoned 0xAA each call)
    hipMemsetAsync(ws, 0, OFF_HDN, stream);

    detect_mask_k<<<1, 64, 0, stream>>>((const unsigned*)mask, flag);
    blend_k<<<BS_, 192, 0, stream>>>(x, mask, hid, emb, flag, hdn);
    cvt_k<<<3072, 256, 0, stream>>>(Wih0, w0b, G4_ * E_);
    cvt_k<<<4096, 256, 0, stream>>>(Whh0, wh0b, G4_ * H_);
    cvt_k<<<4096, 256, 0, stream>>>(Wih1, w1ib, G4_ * H_);
    cvt_k<<<4096, 256, 0, stream>>>(Whh1, wh1b, G4_ * H_);
    cvt_k<<<100, 256, 0, stream>>>(W1, w1ab, 100 * H_);

    // G = hdn @ Wih0^T   [16384,768]x[4096,768]^T
    gemm_k<0><<<dim3(BS_ / 128, G4_ / 128), 256, 0, stream>>>(hdn, w0b, Gb, E_, G4_, G4_, nullptr, 0);

    {   // layer 0 recurrence
        const unsigned short* a0 = Gb; const unsigned short* a1p = wh0b;
        const float* a2 = bih0; const float* a3 = bhh0;
        unsigned short* a4 = out1b; float* a5 = nullptr;
        unsigned short* a6 = h0a; unsigned short* a7 = h0b; unsigned* a8 = bar0;
        void* args[] = {&a0, &a1p, &a2, &a3, &a4, &a5, &a6, &a7, &a8};
        hipLaunchCooperativeKernel((const void*)recur_k, dim3(NWG_), dim3(256), args, 0, stream);
    }

    // G = out1 @ Wih1^T  [16384,1024]x[4096,1024]^T
    gemm_k<0><<<dim3(BS_ / 128, G4_ / 128), 256, 0, stream>>>(out1b, w1ib, Gb, H_, G4_, G4_, nullptr, 0);

    {   // layer 1 recurrence (fp32 out for attention path)
        const unsigned short* a0 = Gb; const unsigned short* a1p = wh1b;
        const float* a2 = bih1; const float* a3 = bhh1;
        unsigned short* a4 = nullptr; float* a5 = out2f;
        unsigned short* a6 = h1a; unsigned short* a7 = h1b; unsigned* a8 = bar1;
        void* args[] = {&a0, &a1p, &a2, &a3, &a4, &a5, &a6, &a7, &a8};
        hipLaunchCooperativeKernel((const void*)recur_k, dim3(NWG_), dim3(256), args, 0, stream);
    }

    // a1 = tanh(out2 @ W1^T + b1)   N=100 (stored with ldc=128)
    gemm_k<1><<<dim3(BS_ / 128, 1), 256, 0, stream>>>(out2f, w1ab, a1b, H_, 100, 128, b1, 1);
    score_k<<<BS_ / 256, 256, 0, stream>>>(a1b, W2, scb);
    attn_k<<<B_, 256, 0, stream>>>(scb, out2f, Wf, bfp, out);

    (void)in_sizes; (void)n_in; (void)out_size; (void)ws_size;
}

// Round 2
// 7792.035 us; speedup vs baseline: 5.4673x; 5.4673x over previous
//
#include <hip/hip_runtime.h>

// ---------------- problem constants ----------------
#define B_   32
#define S_   512
#define E_   768
#define H_   1024
#define G4_  4096          // 4*H
#define BS_  16384         // B*S
#define NWG_ 256           // workgroups in cooperative recurrence

// ---------------- helpers ----------------
__device__ __forceinline__ unsigned short f2b(float f) {
    union { float f; unsigned u; } a; a.f = f;
    unsigned r = a.u + 0x7FFFu + ((a.u >> 16) & 1u);   // round-to-nearest-even
    return (unsigned short)(r >> 16);
}
__device__ __forceinline__ float b2f(unsigned short u) {
    union { unsigned u; float f; } a; a.u = ((unsigned)u) << 16;
    return a.f;
}

typedef __attribute__((ext_vector_type(8))) short bh8;   // 8 x bf16 (4 VGPRs)
typedef __attribute__((ext_vector_type(4))) float f4x;   // MFMA f32 accumulator

// ---------------- mask dtype detection ----------------
__global__ void detect_mask_k(const unsigned* __restrict__ m, unsigned* __restrict__ flag) {
    int t = threadIdx.x;                 // 64 threads
    unsigned bad = 0;
#pragma unroll
    for (int i = 0; i < 4; ++i) { unsigned v = m[t * 4 + i]; bad |= (v > 1u); }
    unsigned long long bb = __ballot(bad != 0u);
    if (t == 0) flag[0] = (bb != 0ull) ? 1u : 0u;
}

// ---------------- blend: hdn = where(emo & s>=1, (emb+hid)*0.5, hid), bf16 out ----------------
__global__ void blend_k(const int* __restrict__ x, const void* __restrict__ mask,
                        const float* __restrict__ hid, const float* __restrict__ emb,
                        const unsigned* __restrict__ flag, unsigned short* __restrict__ hdn) {
    int row = blockIdx.x;                // b*512 + s
    int t = threadIdx.x;                 // 192 threads, 4 floats each (768)
    if (t >= 192) return;
    int s = row & 511;
    int tok = x[row];
    bool emo;
    if (flag[0]) emo = ((const unsigned char*)mask)[tok] != 0;
    else         emo = ((const int*)mask)[tok] != 0;
    bool bl = emo && (s >= 1);
    float4 v = *(const float4*)(hid + (size_t)row * E_ + t * 4);
    if (bl) {
        float4 e = *(const float4*)(emb + (size_t)tok * E_ + t * 4);
        v.x = (v.x + e.x) * 0.5f; v.y = (v.y + e.y) * 0.5f;
        v.z = (v.z + e.z) * 0.5f; v.w = (v.w + e.w) * 0.5f;
    }
    ushort4 o; o.x = f2b(v.x); o.y = f2b(v.y); o.z = f2b(v.z); o.w = f2b(v.w);
    *(ushort4*)(hdn + (size_t)row * E_ + t * 4) = o;
}

// ---------------- f32 -> bf16 weight conversion ----------------
__global__ void cvt_k(const float* __restrict__ in, unsigned short* __restrict__ o, int n) {
    int i = (blockIdx.x * blockDim.x + threadIdx.x) * 4;
    if (i >= n) return;
    float4 v = *(const float4*)(in + i);
    ushort4 u; u.x = f2b(v.x); u.y = f2b(v.y); u.z = f2b(v.z); u.w = f2b(v.w);
    *(ushort4*)(o + i) = u;
}

// ---------------- bf16 MFMA GEMM:  C[M,N] = A[M,K] @ B[N,K]^T  ----------------
template <int AF32>
__global__ __launch_bounds__(256) void gemm_k(const void* __restrict__ Ap,
        const unsigned short* __restrict__ Bp, unsigned short* __restrict__ Cp,
        int K, int Nreal, int ldc, const float* __restrict__ bias, int act) {
    __shared__ char smA[16384];
    __shared__ char smB[16384];
    const int tid = threadIdx.x, l = tid & 63, w = tid >> 6;
    const int m0 = blockIdx.x * 128, n0 = blockIdx.y * 128;
    const int wr = (w >> 1) * 64, wc = (w & 1) * 64;
    f4x acc[4][4] = {};
    for (int k0 = 0; k0 < K; k0 += 64) {
#pragma unroll
        for (int it = 0; it < 4; ++it) {
            int idx = it * 256 + tid;            // 0..1023 : 128 rows x 8 x 16B
            int row = idx >> 3, c16 = idx & 7;
            int sof = (row * 128 + c16 * 16) ^ ((row & 7) << 4);
            bh8 va;
            if (AF32) {
                const float* ap = (const float*)Ap + (size_t)(m0 + row) * K + k0 + c16 * 8;
                float4 f0 = *(const float4*)ap;
                float4 f1 = *(const float4*)(ap + 4);
                va[0] = (short)f2b(f0.x); va[1] = (short)f2b(f0.y);
                va[2] = (short)f2b(f0.z); va[3] = (short)f2b(f0.w);
                va[4] = (short)f2b(f1.x); va[5] = (short)f2b(f1.y);
                va[6] = (short)f2b(f1.z); va[7] = (short)f2b(f1.w);
            } else {
                va = *(const bh8*)((const unsigned short*)Ap + (size_t)(m0 + row) * K + k0 + c16 * 8);
            }
            *(bh8*)(smA + sof) = va;
            int nr = n0 + row;
            bh8 vb = {0, 0, 0, 0, 0, 0, 0, 0};
            if (nr < Nreal) vb = *(const bh8*)(Bp + (size_t)nr * K + k0 + c16 * 8);
            *(bh8*)(smB + sof) = vb;
        }
        __syncthreads();
#pragma unroll
        for (int kk = 0; kk < 2; ++kk) {
            bh8 af[4], bf8[4];
#pragma unroll
            for (int f = 0; f < 4; ++f) {
                int ra = wr + f * 16 + (l & 15);
                af[f] = *(const bh8*)(smA + ((ra * 128 + kk * 64 + ((l >> 4) << 4)) ^ ((ra & 7) << 4)));
                int rb = wc + f * 16 + (l & 15);
                bf8[f] = *(const bh8*)(smB + ((rb * 128 + kk * 64 + ((l >> 4) << 4)) ^ ((rb & 7) << 4)));
            }
#pragma unroll
            for (int fi = 0; fi < 4; ++fi)
#pragma unroll
                for (int fj = 0; fj < 4; ++fj)
                    acc[fi][fj] = __builtin_amdgcn_mfma_f32_16x16x32_bf16(af[fi], bf8[fj], acc[fi][fj], 0, 0, 0);
        }
        __syncthreads();
    }
    // epilogue: C/D layout: col = lane&15, row = (lane>>4)*4 + reg
#pragma unroll
    for (int fi = 0; fi < 4; ++fi) {
        int rb2 = wr + fi * 16 + ((l >> 4) << 2);
#pragma unroll
        for (int fj = 0; fj < 4; ++fj) {
            int cc = n0 + wc + fj * 16 + (l & 15);
            if (cc < Nreal) {
                float bv = bias ? bias[cc] : 0.f;
#pragma unroll
                for (int i = 0; i < 4; ++i) {
                    float xv = acc[fi][fj][i] + bv;
                    if (act) xv = tanhf(xv);
                    Cp[(size_t)(m0 + rb2 + i) * ldc + cc] = f2b(xv);
                }
            }
        }
    }
}

// ---------------- fence-free grid barrier ----------------
// bar[0..15]: L1 counters (16 WGs each); bar[32]: root (128B away); bar[64]: gen flag (256B away).
// All RELAXED agent-scope atomics: per-instruction coherence (sc1), NO buffer_wbl2/buffer_inv.
// Ordering: __syncthreads() drains vmcnt(0) (h stores are sc1 write-through) before arrive.
__device__ __forceinline__ void gridbar(unsigned* bar, unsigned gen) {
    __syncthreads();
    if (threadIdx.x == 0) {
        unsigned a = __hip_atomic_fetch_add(&bar[blockIdx.x & 15], 1u, __ATOMIC_RELAXED, __HIP_MEMORY_SCOPE_AGENT);
        if ((a & 15u) == 15u) {
            unsigned r = __hip_atomic_fetch_add(&bar[32], 1u, __ATOMIC_RELAXED, __HIP_MEMORY_SCOPE_AGENT);
            if ((r & 15u) == 15u)
                __hip_atomic_store(&bar[64], gen, __ATOMIC_RELAXED, __HIP_MEMORY_SCOPE_AGENT);
        }
        while (__hip_atomic_load(&bar[64], __ATOMIC_RELAXED, __HIP_MEMORY_SCOPE_AGENT) < gen)
            __builtin_amdgcn_s_sleep(1);
    }
    __syncthreads();
}

// ---------------- persistent cooperative LSTM recurrence (one layer) ----------------
// h exchange uses a FRESH buffer per step (h32[t][32][512] u32): readers' caches can never
// hold a stale copy of a never-before-read address, so reads are plain cached loads; writes
// are relaxed agent atomics (sc1 write-through). No fences anywhere.
__global__ __launch_bounds__(256) void recur_k(const unsigned short* __restrict__ G,
        const unsigned short* __restrict__ Whh, const float* __restrict__ bih,
        const float* __restrict__ bhh, unsigned short* outb, float* outf,
        unsigned* __restrict__ h32, unsigned* bar) {
    const int wg = blockIdx.x, tid = threadIdx.x, l = tid & 63, wv = tid >> 6;
    __shared__ char  whh_s[32768];                 // 16 rows x 1024 bf16, swizzled
    __shared__ float red_s[4][2][16][16];          // per-wave K-partials
    __shared__ float gates_s[32][16];
    __shared__ float c_s[128];                     // fp32 cell state [b][u]
    __shared__ float bias_s[16];
    // load Whh slice: row n -> global gate row (n>>2)*1024 + wg*4 + (n&3)
#pragma unroll
    for (int it = 0; it < 8; ++it) {
        int idx = it * 256 + tid;                  // 0..2047 : 16 rows x 128 x 16B
        int row = idx >> 7, c16 = idx & 127;
        int Rg = ((row >> 2) << 10) + (wg << 2) + (row & 3);
        bh8 v = *(const bh8*)(Whh + (size_t)Rg * H_ + c16 * 8);
        *(bh8*)(whh_s + ((row * 2048 + c16 * 16) ^ ((row & 7) << 4))) = v;
    }
    if (tid < 16) {
        int Rg = ((tid >> 2) << 10) + (wg << 2) + (tid & 3);
        bias_s[tid] = bih[Rg] + bhh[Rg];
    }
    if (tid < 128) c_s[tid] = 0.f;
    if (tid < 64) {                                // zero own slice of h[0]
        int b = tid >> 1, p = tid & 1;
        __hip_atomic_store(&h32[(size_t)b * 512 + (wg << 1) + p], 0u,
                           __ATOMIC_RELAXED, __HIP_MEMORY_SCOPE_AGENT);
    }
    gridbar(bar, 1);

    // per-thread G gather: one aligned u32 (2 gate values) per step, prefetched 1 step ahead
    const int bg = tid >> 3, n0 = (tid * 2) & 15;
    const size_t gbase = (size_t)(((n0 >> 2) << 10) + (wg << 2) + (n0 & 3));
    unsigned gcur = *(const unsigned*)(G + (size_t)bg * 512 * G4_ + gbase);

    for (int t = 0; t < S_; ++t) {
        int tn = (t + 1 < S_) ? t + 1 : t;
        unsigned gnext = *(const unsigned*)(G + ((size_t)bg * 512 + tn) * G4_ + gbase);
        const char* hpc = (const char*)(h32 + (size_t)t * 16384);
        f4x a0 = {0.f, 0.f, 0.f, 0.f}, a1v = {0.f, 0.f, 0.f, 0.f};
        const int kch = (l >> 4) << 4;
#pragma unroll
        for (int s = 0; s < 8; ++s) {
            int kb = (wv * 256 + s * 32) * 2 + kch;
            bh8 x0 = *(const bh8*)(hpc + (l & 15) * 2048 + kb);
            bh8 x1 = *(const bh8*)(hpc + (16 + (l & 15)) * 2048 + kb);
            bh8 wq = *(const bh8*)(whh_s + (((l & 15) * 2048 + kb) ^ (((l & 15) & 7) << 4)));
            a0  = __builtin_amdgcn_mfma_f32_16x16x32_bf16(x0, wq, a0, 0, 0, 0);
            a1v = __builtin_amdgcn_mfma_f32_16x16x32_bf16(x1, wq, a1v, 0, 0, 0);
        }
#pragma unroll
        for (int i = 0; i < 4; ++i) {
            red_s[wv][0][((l >> 4) << 2) + i][l & 15] = a0[i];
            red_s[wv][1][((l >> 4) << 2) + i][l & 15] = a1v[i];
        }
        __syncthreads();
        {   // reduce K-partials + prefetched G + bias (this thread owns gates (bg, n0), (bg, n0+1))
            int hb = bg >> 4, rb = bg & 15;
            float s0 = red_s[0][hb][rb][n0] + red_s[1][hb][rb][n0]
                     + red_s[2][hb][rb][n0] + red_s[3][hb][rb][n0];
            float s1 = red_s[0][hb][rb][n0 + 1] + red_s[1][hb][rb][n0 + 1]
                     + red_s[2][hb][rb][n0 + 1] + red_s[3][hb][rb][n0 + 1];
            gates_s[bg][n0]     = s0 + b2f((unsigned short)(gcur & 0xffffu)) + bias_s[n0];
            gates_s[bg][n0 + 1] = s1 + b2f((unsigned short)(gcur >> 16)) + bias_s[n0 + 1];
        }
        __syncthreads();
        if (tid < 128) {                           // (b,u): b = tid>>2, u = tid&3
            int b = tid >> 2, u = tid & 3;
            float gi = gates_s[b][u],     gf = gates_s[b][4 + u];
            float gg = gates_s[b][8 + u], go = gates_s[b][12 + u];
            float si = 1.f / (1.f + __expf(-gi));
            float sf = 1.f / (1.f + __expf(-gf));
            float so = 1.f / (1.f + __expf(-go));
            float c = sf * c_s[tid] + si * tanhf(gg);
            float hv = so * tanhf(c);
            c_s[tid] = c;
            unsigned hu = f2b(hv);
            unsigned nb = __shfl_down(hu, 1);
            if ((u & 1) == 0)
                __hip_atomic_store(&h32[(size_t)(t + 1) * 16384 + b * 512 + (wg << 1) + (u >> 1)],
                                   hu | (nb << 16), __ATOMIC_RELAXED, __HIP_MEMORY_SCOPE_AGENT);
            int col = (wg << 2) + u;
            if (outb) outb[((size_t)b * S_ + t) * H_ + col] = (unsigned short)hu;
            if (outf) outf[((size_t)b * S_ + t) * H_ + col] = hv;
        }
        gridbar(bar, (unsigned)(t + 2));           // syncthreads inside drains vmcnt (sc1 stores done)
        gcur = gnext;
    }
}

// ---------------- attention score:  sc[row] = sum_r a1[row,r]*W2[r]  (b2 cancels in softmax) ----------------
__global__ void score_k(const unsigned short* __restrict__ a1, const float* __restrict__ W2,
                        float* __restrict__ sc) {
    int r = blockIdx.x * blockDim.x + threadIdx.x;   // 0..16383
    const unsigned short* p = a1 + (size_t)r * 128;
    float s = 0.f;
#pragma unroll
    for (int i = 0; i < 100; ++i) s += b2f(p[i]) * W2[i];
    sc[r] = s;
}

// ---------------- per-batch: softmax over S -> w ; sent = sum_s w*out2 ; logits ----------------
__global__ __launch_bounds__(256) void attn_k(const float* __restrict__ sc,
        const float* __restrict__ out2, const float* __restrict__ Wf,
        const float* __restrict__ bf, float* __restrict__ out) {
    int b = blockIdx.x, t = threadIdx.x;
    __shared__ float p[512];
    __shared__ float red[256];
    __shared__ float sent[1024];
    float s0 = sc[b * 512 + t], s1 = sc[b * 512 + 256 + t];
    red[t] = fmaxf(s0, s1);
    __syncthreads();
    for (int o = 128; o > 0; o >>= 1) { if (t < o) red[t] = fmaxf(red[t], red[t + o]); __syncthreads(); }
    float M = red[0];
    __syncthreads();
    float e0 = __expf(s0 - M), e1 = __expf(s1 - M);
    red[t] = e0 + e1;
    __syncthreads();
    for (int o = 128; o > 0; o >>= 1) { if (t < o) red[t] += red[t + o]; __syncthreads(); }
    float inv = 1.f / red[0];
    float w0 = e0 * inv, w1 = e1 * inv;
    p[t] = w0; p[t + 256] = w1;
    out[160 + b * 512 + t] = w0;
    out[160 + b * 512 + 256 + t] = w1;
    __syncthreads();
    float4 acc = {0.f, 0.f, 0.f, 0.f};
    for (int s = 0; s < 512; ++s) {
        float ws = p[s];
        float4 v = *(const float4*)(out2 + ((size_t)b * 512 + s) * H_ + t * 4);
        acc.x += ws * v.x; acc.y += ws * v.y; acc.z += ws * v.z; acc.w += ws * v.w;
    }
    *(float4*)(sent + t * 4) = acc;
    __syncthreads();
    int wv = t >> 6, ln = t & 63;
    for (int n = wv; n < 5; n += 4) {
        float prt = 0.f;
        for (int k = ln; k < 1024; k += 64) prt += sent[k] * Wf[n * 1024 + k];
#pragma unroll
        for (int o = 32; o > 0; o >>= 1) prt += __shfl_down(prt, o);
        if (ln == 0) out[b * 5 + n] = prt + bf[n];
    }
}

// ---------------- workspace layout (bytes) ----------------
#define OFF_FLAG  ((size_t)0)
#define OFF_BAR0  ((size_t)256)
#define OFF_BAR1  ((size_t)768)
#define OFF_WH0   ((size_t)4096)
#define OFF_W1I   (OFF_WH0 + (size_t)G4_ * H_ * 2)        // 8.4MB
#define OFF_WH1   (OFF_W1I + (size_t)G4_ * H_ * 2)
#define OFF_W1A   (OFF_WH1 + (size_t)G4_ * H_ * 2)
#define OFF_G     (OFF_W1A + (size_t)262144)              // bf16 [16384][4096] 134MB
#define OFF_OUT1  (OFF_G + (size_t)BS_ * G4_ * 2)         // bf16 [16384][1024] 33.6MB
#define OFF_OUT2  (OFF_OUT1 + (size_t)BS_ * H_ * 2)       // f32  [16384][1024] 67MB
#define OFF_A1    (OFF_OUT2 + (size_t)BS_ * H_ * 4)       // bf16 [16384][128]   4.2MB
#define OFF_SC    (OFF_A1 + (size_t)BS_ * 128 * 2)        // f32  [16384]
#define OFF_HDN   (OFF_SC + (size_t)65536)                // bf16 [16384][768]  25.2MB (dead after gemm0)
#define OFF_W0    (OFF_HDN + (size_t)BS_ * E_ * 2)        // Wih0b 6.3MB        (dead after gemm0)
#define OFF_H32   OFF_HDN                                 // u32 [513][32][512] 33.6MB, overlays hdn+w0

extern "C" void kernel_launch(void* const* d_in, const int* in_sizes, int n_in,
                              void* d_out, int out_size, void* d_ws, size_t ws_size,
                              hipStream_t stream) {
    const int*   x    = (const int*)d_in[0];
    const void*  mask = d_in[1];
    const float* hid  = (const float*)d_in[2];
    const float* emb  = (const float*)d_in[3];
    const float* Wih0 = (const float*)d_in[4];
    const float* Whh0 = (const float*)d_in[5];
    const float* bih0 = (const float*)d_in[6];
    const float* bhh0 = (const float*)d_in[7];
    const float* Wih1 = (const float*)d_in[8];
    const float* Whh1 = (const float*)d_in[9];
    const float* bih1 = (const float*)d_in[10];
    const float* bhh1 = (const float*)d_in[11];
    const float* W1   = (const float*)d_in[12];
    const float* b1   = (const float*)d_in[13];
    const float* W2   = (const float*)d_in[14];
    const float* Wf   = (const float*)d_in[16];
    const float* bfp  = (const float*)d_in[17];
    float* out = (float*)d_out;
    char* ws = (char*)d_ws;

    unsigned*       bar0  = (unsigned*)(ws + OFF_BAR0);
    unsigned*       bar1  = (unsigned*)(ws + OFF_BAR1);
    unsigned*       flag  = (unsigned*)(ws + OFF_FLAG);
    unsigned short* wh0b  = (unsigned short*)(ws + OFF_WH0);
    unsigned short* w1ib  = (unsigned short*)(ws + OFF_W1I);
    unsigned short* wh1b  = (unsigned short*)(ws + OFF_WH1);
    unsigned short* w1ab  = (unsigned short*)(ws + OFF_W1A);
    unsigned short* Gb    = (unsigned short*)(ws + OFF_G);
    unsigned short* out1b = (unsigned short*)(ws + OFF_OUT1);
    float*          out2f = (float*)(ws + OFF_OUT2);
    unsigned short* a1b   = (unsigned short*)(ws + OFF_A1);
    float*          scb   = (float*)(ws + OFF_SC);
    unsigned short* hdn   = (unsigned short*)(ws + OFF_HDN);
    unsigned short* w0b   = (unsigned short*)(ws + OFF_W0);
    unsigned*       h32   = (unsigned*)(ws + OFF_H32);

    // zero flag + both barrier regions (re-poisoned 0xAA each call)
    hipMemsetAsync(ws, 0, 4096, stream);

    detect_mask_k<<<1, 64, 0, stream>>>((const unsigned*)mask, flag);
    blend_k<<<BS_, 192, 0, stream>>>(x, mask, hid, emb, flag, hdn);
    cvt_k<<<3072, 256, 0, stream>>>(Wih0, w0b, G4_ * E_);
    cvt_k<<<4096, 256, 0, stream>>>(Whh0, wh0b, G4_ * H_);
    cvt_k<<<4096, 256, 0, stream>>>(Wih1, w1ib, G4_ * H_);
    cvt_k<<<4096, 256, 0, stream>>>(Whh1, wh1b, G4_ * H_);
    cvt_k<<<100, 256, 0, stream>>>(W1, w1ab, 100 * H_);

    // G = hdn @ Wih0^T   [16384,768]x[4096,768]^T
    gemm_k<0><<<dim3(BS_ / 128, G4_ / 128), 256, 0, stream>>>(hdn, w0b, Gb, E_, G4_, G4_, nullptr, 0);

    {   // layer 0 recurrence (h32 overlays hdn/w0b — both dead now)
        const unsigned short* a0 = Gb; const unsigned short* a1p = wh0b;
        const float* a2 = bih0; const float* a3 = bhh0;
        unsigned short* a4 = out1b; float* a5 = nullptr;
        unsigned* a6 = h32; unsigned* a7 = bar0;
        void* args[] = {&a0, &a1p, &a2, &a3, &a4, &a5, &a6, &a7};
        hipLaunchCooperativeKernel((const void*)recur_k, dim3(NWG_), dim3(256), args, 0, stream);
    }

    // G = out1 @ Wih1^T  [16384,1024]x[4096,1024]^T
    gemm_k<0><<<dim3(BS_ / 128, G4_ / 128), 256, 0, stream>>>(out1b, w1ib, Gb, H_, G4_, G4_, nullptr, 0);

    {   // layer 1 recurrence (fp32 out for attention path)
        const unsigned short* a0 = Gb; const unsigned short* a1p = wh1b;
        const float* a2 = bih1; const float* a3 = bhh1;
        unsigned short* a4 = nullptr; float* a5 = out2f;
        unsigned* a6 = h32; unsigned* a7 = bar1;
        void* args[] = {&a0, &a1p, &a2, &a3, &a4, &a5, &a6, &a7};
        hipLaunchCooperativeKernel((const void*)recur_k, dim3(NWG_), dim3(256), args, 0, stream);
    }

    // a1 = tanh(out2 @ W1^T + b1)   N=100 (stored with ldc=128)
    gemm_k<1><<<dim3(BS_ / 128, 1), 256, 0, stream>>>(out2f, w1ab, a1b, H_, 100, 128, b1, 1);
    score_k<<<BS_ / 256, 256, 0, stream>>>(a1b, W2, scb);
    attn_k<<<B_, 256, 0, stream>>>(scb, out2f, Wf, bfp, out);

    (void)in_sizes; (void)n_in; (void)out_size; (void)ws_size;
}

// Round 3
// 5697.255 us; speedup vs baseline: 7.4776x; 1.3677x over previous
//
#include <hip/hip_runtime.h>

// ---------------- problem constants ----------------
#define B_   32
#define S_   512
#define E_   768
#define H_   1024
#define G4_  4096          // 4*H
#define BS_  16384         // B*S

// ---------------- helpers ----------------
__device__ __forceinline__ unsigned short f2b(float f) {
    union { float f; unsigned u; } a; a.f = f;
    unsigned r = a.u + 0x7FFFu + ((a.u >> 16) & 1u);   // round-to-nearest-even
    return (unsigned short)(r >> 16);
}
__device__ __forceinline__ float b2f(unsigned short u) {
    union { unsigned u; float f; } a; a.u = ((unsigned)u) << 16;
    return a.f;
}

typedef __attribute__((ext_vector_type(8))) short bh8;   // 8 x bf16 (4 VGPRs)
typedef __attribute__((ext_vector_type(4))) float f4x;   // MFMA f32 accumulator

#define ALOAD(p)     __hip_atomic_load((p), __ATOMIC_RELAXED, __HIP_MEMORY_SCOPE_AGENT)
#define ASTORE(p, v) __hip_atomic_store((p), (v), __ATOMIC_RELAXED, __HIP_MEMORY_SCOPE_AGENT)

// ---------------- mask dtype detection ----------------
__global__ void detect_mask_k(const unsigned* __restrict__ m, unsigned* __restrict__ flag) {
    int t = threadIdx.x;                 // 64 threads
    unsigned bad = 0;
#pragma unroll
    for (int i = 0; i < 4; ++i) { unsigned v = m[t * 4 + i]; bad |= (v > 1u); }
    unsigned long long bb = __ballot(bad != 0u);
    if (t == 0) flag[0] = (bb != 0ull) ? 1u : 0u;
}

// ---------------- blend: hdn = where(emo & s>=1, (emb+hid)*0.5, hid), bf16 out ----------------
__global__ void blend_k(const int* __restrict__ x, const void* __restrict__ mask,
                        const float* __restrict__ hid, const float* __restrict__ emb,
                        const unsigned* __restrict__ flag, unsigned short* __restrict__ hdn) {
    int row = blockIdx.x;                // b*512 + s
    int t = threadIdx.x;                 // 192 threads, 4 floats each (768)
    if (t >= 192) return;
    int s = row & 511;
    int tok = x[row];
    bool emo;
    if (flag[0]) emo = ((const unsigned char*)mask)[tok] != 0;
    else         emo = ((const int*)mask)[tok] != 0;
    bool bl = emo && (s >= 1);
    float4 v = *(const float4*)(hid + (size_t)row * E_ + t * 4);
    if (bl) {
        float4 e = *(const float4*)(emb + (size_t)tok * E_ + t * 4);
        v.x = (v.x + e.x) * 0.5f; v.y = (v.y + e.y) * 0.5f;
        v.z = (v.z + e.z) * 0.5f; v.w = (v.w + e.w) * 0.5f;
    }
    ushort4 o; o.x = f2b(v.x); o.y = f2b(v.y); o.z = f2b(v.z); o.w = f2b(v.w);
    *(ushort4*)(hdn + (size_t)row * E_ + t * 4) = o;
}

// ---------------- f32 -> bf16 weight conversion ----------------
__global__ void cvt_k(const float* __restrict__ in, unsigned short* __restrict__ o, int n) {
    int i = (blockIdx.x * blockDim.x + threadIdx.x) * 4;
    if (i >= n) return;
    float4 v = *(const float4*)(in + i);
    ushort4 u; u.x = f2b(v.x); u.y = f2b(v.y); u.z = f2b(v.z); u.w = f2b(v.w);
    *(ushort4*)(o + i) = u;
}

// ---------------- bf16 MFMA GEMM:  C[M,N] = A[M,K] @ B[N,K]^T ----------------
// PERM=1: permute output column n = gate*1024 + w*8 + uu  ->  n' = w*32 + gate*8 + uu
// so that each recurrence-WG's 32 gate values per row are one contiguous 64B line.
template <int AF32, int PERM>
__global__ __launch_bounds__(256) void gemm_k(const void* __restrict__ Ap,
        const unsigned short* __restrict__ Bp, unsigned short* __restrict__ Cp,
        int K, int Nreal, int ldc, const float* __restrict__ bias, int act) {
    __shared__ char smA[16384];
    __shared__ char smB[16384];
    const int tid = threadIdx.x, l = tid & 63, w = tid >> 6;
    const int m0 = blockIdx.x * 128, n0 = blockIdx.y * 128;
    const int wr = (w >> 1) * 64, wc = (w & 1) * 64;
    f4x acc[4][4] = {};
    for (int k0 = 0; k0 < K; k0 += 64) {
#pragma unroll
        for (int it = 0; it < 4; ++it) {
            int idx = it * 256 + tid;            // 0..1023 : 128 rows x 8 x 16B
            int row = idx >> 3, c16 = idx & 7;
            int sof = (row * 128 + c16 * 16) ^ ((row & 7) << 4);
            bh8 va;
            if (AF32) {
                const float* ap = (const float*)Ap + (size_t)(m0 + row) * K + k0 + c16 * 8;
                float4 f0 = *(const float4*)ap;
                float4 f1 = *(const float4*)(ap + 4);
                va[0] = (short)f2b(f0.x); va[1] = (short)f2b(f0.y);
                va[2] = (short)f2b(f0.z); va[3] = (short)f2b(f0.w);
                va[4] = (short)f2b(f1.x); va[5] = (short)f2b(f1.y);
                va[6] = (short)f2b(f1.z); va[7] = (short)f2b(f1.w);
            } else {
                va = *(const bh8*)((const unsigned short*)Ap + (size_t)(m0 + row) * K + k0 + c16 * 8);
            }
            *(bh8*)(smA + sof) = va;
            int nr = n0 + row;
            bh8 vb = {0, 0, 0, 0, 0, 0, 0, 0};
            if (nr < Nreal) vb = *(const bh8*)(Bp + (size_t)nr * K + k0 + c16 * 8);
            *(bh8*)(smB + sof) = vb;
        }
        __syncthreads();
#pragma unroll
        for (int kk = 0; kk < 2; ++kk) {
            bh8 af[4], bf8[4];
#pragma unroll
            for (int f = 0; f < 4; ++f) {
                int ra = wr + f * 16 + (l & 15);
                af[f] = *(const bh8*)(smA + ((ra * 128 + kk * 64 + ((l >> 4) << 4)) ^ ((ra & 7) << 4)));
                int rb = wc + f * 16 + (l & 15);
                bf8[f] = *(const bh8*)(smB + ((rb * 128 + kk * 64 + ((l >> 4) << 4)) ^ ((rb & 7) << 4)));
            }
#pragma unroll
            for (int fi = 0; fi < 4; ++fi)
#pragma unroll
                for (int fj = 0; fj < 4; ++fj)
                    acc[fi][fj] = __builtin_amdgcn_mfma_f32_16x16x32_bf16(af[fi], bf8[fj], acc[fi][fj], 0, 0, 0);
        }
        __syncthreads();
    }
    // epilogue: C/D layout: col = lane&15, row = (lane>>4)*4 + reg
#pragma unroll
    for (int fi = 0; fi < 4; ++fi) {
        int rb2 = wr + fi * 16 + ((l >> 4) << 2);
#pragma unroll
        for (int fj = 0; fj < 4; ++fj) {
            int cc = n0 + wc + fj * 16 + (l & 15);
            if (cc < Nreal) {
                float bv = bias ? bias[cc] : 0.f;
                int cw = cc;
                if (PERM) {
                    int gate = cc >> 10, rem = cc & 1023;
                    cw = (rem >> 3) * 32 + gate * 8 + (cc & 7);
                }
#pragma unroll
                for (int i = 0; i < 4; ++i) {
                    float xv = acc[fi][fj][i] + bv;
                    if (act) xv = tanhf(xv);
                    Cp[(size_t)(m0 + rb2 + i) * ldc + cw] = f2b(xv);
                }
            }
        }
    }
}

// ---------------- fused 2-layer persistent LSTM recurrence ----------------
// 256 WGs x 256 thr. WGs 0..127: layer 0 (8 hidden units each, Whh0 slice in LDS,
// gate input from precomputed permuted G). WGs 128..255: layer 1 (8 units,
// Wih1 + Whh1 slices in LDS, 128KB; input = out1[t] read directly from h0 step
// buffers -> layer-1 lags layer 0 by one generation; no middle GEMM needed).
// Synchronization: per-WG monotonic slot stores + distributed sc1 polling
// (no atomic RMW, no root counter, no gen flag). h step buffers are fresh per
// step (never-read addresses => plain cached loads are coherent).
// slot[wg] = j+1  where j = highest h index published by wg.
__global__ __launch_bounds__(256, 1) void recur2_k(
        const unsigned short* __restrict__ G,      // [16384][4096] permuted cols
        const unsigned short* __restrict__ Whh0,
        const float* __restrict__ bih0, const float* __restrict__ bhh0,
        const unsigned short* __restrict__ Wih1,
        const unsigned short* __restrict__ Whh1,
        const float* __restrict__ bih1, const float* __restrict__ bhh1,
        float* __restrict__ out2,
        unsigned* __restrict__ h0b, unsigned* __restrict__ h1b,
        unsigned* __restrict__ slots) {
    __shared__ __align__(16) char w_lds[131072];   // L0: [0,64K)=Whh0 ; L1: Wih1 | Whh1
    __shared__ float red_s[4][32][33];             // per-wave K-partials (padded)
    __shared__ float bias_s[32];
    unsigned short* g_s = (unsigned short*)(w_lds + 65536);   // L0 only (aliases unused half)

    const int tid = threadIdx.x, l = tid & 63, wv = tid >> 6, ln = l;
    const int wg = blockIdx.x, lay = wg >> 7, w = wg & 127;
    const int u0 = w * 8;
    const int q = l >> 4, r0 = l & 15;
    const int bb = tid >> 3, uu = tid & 7;         // cell ownership: (batch, unit)

    // ---- load weight slices (row r = gate*8+uu of own units; XOR-swizzled) ----
#pragma unroll
    for (int it = 0; it < 16; ++it) {
        int idx = it * 256 + tid;                  // 32 rows x 128 chunks of 16B
        int r = idx >> 7, c16 = idx & 127;
        int Rg = (r >> 3) * 1024 + u0 + (r & 7);
        int dst = (r * 2048 + c16 * 16) ^ ((r & 7) << 4);
        if (lay == 0) {
            *(bh8*)(w_lds + dst) = *(const bh8*)(Whh0 + (size_t)Rg * 1024 + c16 * 8);
        } else {
            *(bh8*)(w_lds + dst) = *(const bh8*)(Wih1 + (size_t)Rg * 1024 + c16 * 8);
            *(bh8*)(w_lds + 65536 + dst) = *(const bh8*)(Whh1 + (size_t)Rg * 1024 + c16 * 8);
        }
    }
    if (tid < 32) {
        int Rg = (tid >> 3) * 1024 + u0 + (tid & 7);
        bias_s[tid] = (lay == 0) ? (bih0[Rg] + bhh0[Rg]) : (bih1[Rg] + bhh1[Rg]);
    }
    {   // zero own slice of h[0]
        unsigned* hb = (lay == 0) ? h0b : h1b;
        if (tid < 128) ASTORE(&hb[(size_t)w * 128 + tid], 0u);
    }
    float cS = 0.f;                                // cell state in register
    __syncthreads();                               // drains h[0] stores (vmcnt)
    if (tid == 0) ASTORE(&slots[wg], 1u);

    if (lay == 0) {
        // ---- layer 0: steps s = 0..511 at gen g = s+1 ----
        const int gb = tid >> 2, gq = tid & 3;     // G loader: (batch, 16B-quarter)
        bh8 greg = {};
        if (tid < 128)
            greg = *(const bh8*)(G + (size_t)gb * 512 * G4_ + w * 32 + gq * 8);
        for (int g = 1; g <= 512; ++g) {
            int s = g - 1;
            for (;;) {                             // wait: all L0 slots >= g
                unsigned s0v = ALOAD(&slots[ln]);
                unsigned s1v = ALOAD(&slots[64 + ln]);
                if (__all(s0v >= (unsigned)g && s1v >= (unsigned)g)) break;
                __builtin_amdgcn_s_sleep(2);
            }
            const char* hp = (const char*)h0b + (size_t)(g - 1) * 65536;
            f4x a00 = {}, a01 = {}, a10 = {}, a11 = {};
#pragma unroll
            for (int s8 = 0; s8 < 8; ++s8) {
                int k0 = wv * 256 + s8 * 32 + q * 8;
                int blk = k0 >> 3;
                bh8 x0 = *(const bh8*)(hp + blk * 512 + r0 * 16);
                bh8 x1 = *(const bh8*)(hp + blk * 512 + (16 + r0) * 16);
                bh8 w0 = *(const bh8*)(w_lds + ((r0 * 2048 + k0 * 2) ^ ((r0 & 7) << 4)));
                bh8 w1 = *(const bh8*)(w_lds + (((16 + r0) * 2048 + k0 * 2) ^ ((r0 & 7) << 4)));
                a00 = __builtin_amdgcn_mfma_f32_16x16x32_bf16(x0, w0, a00, 0, 0, 0);
                a01 = __builtin_amdgcn_mfma_f32_16x16x32_bf16(x0, w1, a01, 0, 0, 0);
                a10 = __builtin_amdgcn_mfma_f32_16x16x32_bf16(x1, w0, a10, 0, 0, 0);
                a11 = __builtin_amdgcn_mfma_f32_16x16x32_bf16(x1, w1, a11, 0, 0, 0);
            }
#pragma unroll
            for (int i = 0; i < 4; ++i) {
                int ro = q * 4 + i;
                red_s[wv][ro][r0]           = a00[i];
                red_s[wv][ro][16 + r0]      = a01[i];
                red_s[wv][16 + ro][r0]      = a10[i];
                red_s[wv][16 + ro][16 + r0] = a11[i];
            }
            if (tid < 128) {                       // commit G(s) to LDS, prefetch G(s+1)
                *(bh8*)(g_s + gb * 32 + gq * 8) = greg;
                int sn = (s + 1 < 512) ? s + 1 : s;
                greg = *(const bh8*)(G + ((size_t)gb * 512 + sn) * G4_ + w * 32 + gq * 8);
            }
            __syncthreads();
            float gv[4];
#pragma unroll
            for (int gg = 0; gg < 4; ++gg) {
                int rr = gg * 8 + uu;
                gv[gg] = red_s[0][bb][rr] + red_s[1][bb][rr] + red_s[2][bb][rr] + red_s[3][bb][rr]
                       + b2f(g_s[bb * 32 + rr]) + bias_s[rr];
            }
            float si = 1.f / (1.f + __expf(-gv[0]));
            float sf = 1.f / (1.f + __expf(-gv[1]));
            float so = 1.f / (1.f + __expf(-gv[3]));
            float cn = sf * cS + si * tanhf(gv[2]);
            float hv = so * tanhf(cn);
            cS = cn;
            unsigned hu = f2b(hv);
            unsigned nb = __shfl_down(hu, 1);
            if ((uu & 1) == 0)
                ASTORE(&h0b[(size_t)g * 16384 + w * 128 + bb * 4 + (uu >> 1)], hu | (nb << 16));
            __syncthreads();                       // drains h stores before slot publish
            if (tid == 0) ASTORE(&slots[wg], (unsigned)(g + 1));
        }
    } else {
        // ---- layer 1: steps s = 0..511 at gen g = s+2 (lags layer 0 by one) ----
        for (int g = 2; g <= 513; ++g) {
            int s = g - 2;
            for (;;) {                             // wait: L0 slots >= g, L1 slots >= g-1
                unsigned s0v = ALOAD(&slots[ln]);
                unsigned s1v = ALOAD(&slots[64 + ln]);
                unsigned s2v = ALOAD(&slots[128 + ln]);
                unsigned s3v = ALOAD(&slots[192 + ln]);
                if (__all(s0v >= (unsigned)g && s1v >= (unsigned)g &&
                          s2v >= (unsigned)(g - 1) && s3v >= (unsigned)(g - 1))) break;
                __builtin_amdgcn_s_sleep(2);
            }
            const char* hpA = (const char*)h0b + (size_t)(g - 1) * 65536;  // out1[s] = h0[s+1]
            const char* hpB = (const char*)h1b + (size_t)(g - 2) * 65536;  // h1[s]
            f4x a00 = {}, a01 = {}, a10 = {}, a11 = {};
#pragma unroll
            for (int s8 = 0; s8 < 8; ++s8) {       // K 0..1023: Wih1 @ out1[s]
                int k0 = wv * 256 + s8 * 32 + q * 8;
                int blk = k0 >> 3;
                bh8 x0 = *(const bh8*)(hpA + blk * 512 + r0 * 16);
                bh8 x1 = *(const bh8*)(hpA + blk * 512 + (16 + r0) * 16);
                bh8 w0 = *(const bh8*)(w_lds + ((r0 * 2048 + k0 * 2) ^ ((r0 & 7) << 4)));
                bh8 w1 = *(const bh8*)(w_lds + (((16 + r0) * 2048 + k0 * 2) ^ ((r0 & 7) << 4)));
                a00 = __builtin_amdgcn_mfma_f32_16x16x32_bf16(x0, w0, a00, 0, 0, 0);
                a01 = __builtin_amdgcn_mfma_f32_16x16x32_bf16(x0, w1, a01, 0, 0, 0);
                a10 = __builtin_amdgcn_mfma_f32_16x16x32_bf16(x1, w0, a10, 0, 0, 0);
                a11 = __builtin_amdgcn_mfma_f32_16x16x32_bf16(x1, w1, a11, 0, 0, 0);
            }
#pragma unroll
            for (int s8 = 0; s8 < 8; ++s8) {       // K 0..1023: Whh1 @ h1[s]
                int k0 = wv * 256 + s8 * 32 + q * 8;
                int blk = k0 >> 3;
                bh8 x0 = *(const bh8*)(hpB + blk * 512 + r0 * 16);
                bh8 x1 = *(const bh8*)(hpB + blk * 512 + (16 + r0) * 16);
                bh8 w0 = *(const bh8*)(w_lds + 65536 + ((r0 * 2048 + k0 * 2) ^ ((r0 & 7) << 4)));
                bh8 w1 = *(const bh8*)(w_lds + 65536 + (((16 + r0) * 2048 + k0 * 2) ^ ((r0 & 7) << 4)));
                a00 = __builtin_amdgcn_mfma_f32_16x16x32_bf16(x0, w0, a00, 0, 0, 0);
                a01 = __builtin_amdgcn_mfma_f32_16x16x32_bf16(x0, w1, a01, 0, 0, 0);
                a10 = __builtin_amdgcn_mfma_f32_16x16x32_bf16(x1, w0, a10, 0, 0, 0);
                a11 = __builtin_amdgcn_mfma_f32_16x16x32_bf16(x1, w1, a11, 0, 0, 0);
            }
#pragma unroll
            for (int i = 0; i < 4; ++i) {
                int ro = q * 4 + i;
                red_s[wv][ro][r0]           = a00[i];
                red_s[wv][ro][16 + r0]      = a01[i];
                red_s[wv][16 + ro][r0]      = a10[i];
                red_s[wv][16 + ro][16 + r0] = a11[i];
            }
            __syncthreads();
            float gv[4];
#pragma unroll
            for (int gg = 0; gg < 4; ++gg) {
                int rr = gg * 8 + uu;
                gv[gg] = red_s[0][bb][rr] + red_s[1][bb][rr] + red_s[2][bb][rr] + red_s[3][bb][rr]
                       + bias_s[rr];
            }
            float si = 1.f / (1.f + __expf(-gv[0]));
            float sf = 1.f / (1.f + __expf(-gv[1]));
            float so = 1.f / (1.f + __expf(-gv[3]));
            float cn = sf * cS + si * tanhf(gv[2]);
            float hv = so * tanhf(cn);
            cS = cn;
            unsigned hu = f2b(hv);
            unsigned nb = __shfl_down(hu, 1);
            if ((uu & 1) == 0)
                ASTORE(&h1b[(size_t)(g - 1) * 16384 + w * 128 + bb * 4 + (uu >> 1)], hu | (nb << 16));
            out2[((size_t)bb * 512 + s) * 1024 + u0 + uu] = hv;   // fp32 out for attention
            __syncthreads();
            if (tid == 0) ASTORE(&slots[wg], (unsigned)g);
        }
    }
}

// ---------------- attention score:  sc[row] = sum_r a1[row,r]*W2[r]  (b2 cancels in softmax) ----------------
__global__ void score_k(const unsigned short* __restrict__ a1, const float* __restrict__ W2,
                        float* __restrict__ sc) {
    int r = blockIdx.x * blockDim.x + threadIdx.x;   // 0..16383
    const unsigned short* p = a1 + (size_t)r * 104;
    float s = 0.f;
#pragma unroll
    for (int i = 0; i < 100; ++i) s += b2f(p[i]) * W2[i];
    sc[r] = s;
}

// ---------------- per-batch: softmax over S -> w ; sent = sum_s w*out2 ; logits ----------------
__global__ __launch_bounds__(256) void attn_k(const float* __restrict__ sc,
        const float* __restrict__ out2, const float* __restrict__ Wf,
        const float* __restrict__ bf, float* __restrict__ out) {
    int b = blockIdx.x, t = threadIdx.x;
    __shared__ float p[512];
    __shared__ float red[256];
    __shared__ float sent[1024];
    float s0 = sc[b * 512 + t], s1 = sc[b * 512 + 256 + t];
    red[t] = fmaxf(s0, s1);
    __syncthreads();
    for (int o = 128; o > 0; o >>= 1) { if (t < o) red[t] = fmaxf(red[t], red[t + o]); __syncthreads(); }
    float M = red[0];
    __syncthreads();
    float e0 = __expf(s0 - M), e1 = __expf(s1 - M);
    red[t] = e0 + e1;
    __syncthreads();
    for (int o = 128; o > 0; o >>= 1) { if (t < o) red[t] += red[t + o]; __syncthreads(); }
    float inv = 1.f / red[0];
    float w0 = e0 * inv, w1 = e1 * inv;
    p[t] = w0; p[t + 256] = w1;
    out[160 + b * 512 + t] = w0;
    out[160 + b * 512 + 256 + t] = w1;
    __syncthreads();
    float4 acc = {0.f, 0.f, 0.f, 0.f};
    for (int s = 0; s < 512; ++s) {
        float ws = p[s];
        float4 v = *(const float4*)(out2 + ((size_t)b * 512 + s) * H_ + t * 4);
        acc.x += ws * v.x; acc.y += ws * v.y; acc.z += ws * v.z; acc.w += ws * v.w;
    }
    *(float4*)(sent + t * 4) = acc;
    __syncthreads();
    int wv = t >> 6, ln = t & 63;
    for (int n = wv; n < 5; n += 4) {
        float prt = 0.f;
        for (int k = ln; k < 1024; k += 64) prt += sent[k] * Wf[n * 1024 + k];
#pragma unroll
        for (int o = 32; o > 0; o >>= 1) prt += __shfl_down(prt, o);
        if (ln == 0) out[b * 5 + n] = prt + bf[n];
    }
}

// ---------------- workspace layout (bytes); proven ws_size >= 298,192,896 ----------------
#define OFF_SLOT  ((size_t)0)                              // 256 u32 slots
#define OFF_FLAG  ((size_t)1024)
#define OFF_WH0   ((size_t)4096)                           // 8,388,608
#define OFF_W1I   (OFF_WH0 + (size_t)G4_ * H_ * 2)         // 8,392,704
#define OFF_WH1   (OFF_W1I + (size_t)G4_ * H_ * 2)         // 16,781,312
#define OFF_W1A   (OFF_WH1 + (size_t)G4_ * H_ * 2)         // 25,169,920 (+256KB pad)
#define OFF_G     (OFF_W1A + (size_t)262144)               // 25,432,064 : 134,217,728
#define OFF_OUT2  (OFF_G + (size_t)BS_ * G4_ * 2)          // 159,649,792 : 67,108,864
#define OFF_HDN   OFF_OUT2                                 // hdn (25.2MB) overlays out2 (dead before recur)
#define OFF_W0    (OFF_HDN + (size_t)BS_ * E_ * 2)         // w0b (6.3MB) also inside out2
#define OFF_A1    (OFF_OUT2 + (size_t)BS_ * H_ * 4)        // 226,758,656 : 3,407,872 (ldc=104)
#define OFF_SC    (OFF_A1 + (size_t)BS_ * 104 * 2)         // 230,166,528 : 65,536
#define OFF_H0    ((size_t)230293504)                      // 64KB-aligned : 513*65,536 = 33,619,968
#define OFF_H1    (OFF_H0 + (size_t)513 * 65536)           // 263,913,472 : 33,619,968 -> end 297,533,440

extern "C" void kernel_launch(void* const* d_in, const int* in_sizes, int n_in,
                              void* d_out, int out_size, void* d_ws, size_t ws_size,
                              hipStream_t stream) {
    const int*   x    = (const int*)d_in[0];
    const void*  mask = d_in[1];
    const float* hid  = (const float*)d_in[2];
    const float* emb  = (const float*)d_in[3];
    const float* Wih0 = (const float*)d_in[4];
    const float* Whh0 = (const float*)d_in[5];
    const float* bih0 = (const float*)d_in[6];
    const float* bhh0 = (const float*)d_in[7];
    const float* Wih1 = (const float*)d_in[8];
    const float* Whh1 = (const float*)d_in[9];
    const float* bih1 = (const float*)d_in[10];
    const float* bhh1 = (const float*)d_in[11];
    const float* W1   = (const float*)d_in[12];
    const float* b1   = (const float*)d_in[13];
    const float* W2   = (const float*)d_in[14];
    const float* Wf   = (const float*)d_in[16];
    const float* bfp  = (const float*)d_in[17];
    float* out = (float*)d_out;
    char* ws = (char*)d_ws;

    unsigned*       slots = (unsigned*)(ws + OFF_SLOT);
    unsigned*       flag  = (unsigned*)(ws + OFF_FLAG);
    unsigned short* wh0b  = (unsigned short*)(ws + OFF_WH0);
    unsigned short* w1ib  = (unsigned short*)(ws + OFF_W1I);
    unsigned short* wh1b  = (unsigned short*)(ws + OFF_WH1);
    unsigned short* w1ab  = (unsigned short*)(ws + OFF_W1A);
    unsigned short* Gb    = (unsigned short*)(ws + OFF_G);
    float*          out2f = (float*)(ws + OFF_OUT2);
    unsigned short* hdn   = (unsigned short*)(ws + OFF_HDN);
    unsigned short* w0b   = (unsigned short*)(ws + OFF_W0);
    unsigned short* a1b   = (unsigned short*)(ws + OFF_A1);
    float*          scb   = (float*)(ws + OFF_SC);
    unsigned*       h0b   = (unsigned*)(ws + OFF_H0);
    unsigned*       h1b   = (unsigned*)(ws + OFF_H1);

    hipMemsetAsync(ws, 0, 4096, stream);          // slots + flag

    detect_mask_k<<<1, 64, 0, stream>>>((const unsigned*)mask, flag);
    blend_k<<<BS_, 192, 0, stream>>>(x, mask, hid, emb, flag, hdn);
    cvt_k<<<3072, 256, 0, stream>>>(Wih0, w0b, G4_ * E_);
    cvt_k<<<4096, 256, 0, stream>>>(Whh0, wh0b, G4_ * H_);
    cvt_k<<<4096, 256, 0, stream>>>(Wih1, w1ib, G4_ * H_);
    cvt_k<<<4096, 256, 0, stream>>>(Whh1, wh1b, G4_ * H_);
    cvt_k<<<100, 256, 0, stream>>>(W1, w1ab, 100 * H_);

    // G = hdn @ Wih0^T  (permuted column layout for single-fetch gather in recur)
    gemm_k<0, 1><<<dim3(BS_ / 128, G4_ / 128), 256, 0, stream>>>(hdn, w0b, Gb, E_, G4_, G4_, nullptr, 0);

    {   // fused 2-layer recurrence
        const unsigned short* a0 = Gb;
        const unsigned short* a1p = wh0b;
        const float* a2 = bih0; const float* a3 = bhh0;
        const unsigned short* a4 = w1ib; const unsigned short* a5 = wh1b;
        const float* a6 = bih1; const float* a7 = bhh1;
        float* a8 = out2f; unsigned* a9 = h0b; unsigned* a10 = h1b; unsigned* a11 = slots;
        void* args[] = {&a0, &a1p, &a2, &a3, &a4, &a5, &a6, &a7, &a8, &a9, &a10, &a11};
        hipLaunchCooperativeKernel((const void*)recur2_k, dim3(256), dim3(256), args, 0, stream);
    }

    // a1 = tanh(out2 @ W1^T + b1)   N=100, ldc=104
    gemm_k<1, 0><<<dim3(BS_ / 128, 1), 256, 0, stream>>>(out2f, w1ab, a1b, H_, 100, 104, b1, 1);
    score_k<<<BS_ / 256, 256, 0, stream>>>(a1b, W2, scb);
    attn_k<<<B_, 256, 0, stream>>>(scb, out2f, Wf, bfp, out);

    (void)in_sizes; (void)n_in; (void)out_size; (void)ws_size;
}

// Round 5
// 5592.402 us; speedup vs baseline: 7.6178x; 1.0187x over previous
//
#include <hip/hip_runtime.h>

// ---------------- problem constants ----------------
#define B_   32
#define S_   512
#define E_   768
#define H_   1024
#define G4_  4096          // 4*H
#define BS_  16384         // B*S

// ---------------- helpers ----------------
__device__ __forceinline__ unsigned short f2b(float f) {
    union { float f; unsigned u; } a; a.f = f;
    unsigned r = a.u + 0x7FFFu + ((a.u >> 16) & 1u);   // round-to-nearest-even
    return (unsigned short)(r >> 16);
}
__device__ __forceinline__ float b2f(unsigned short u) {
    union { unsigned u; float f; } a; a.u = ((unsigned)u) << 16;
    return a.f;
}

typedef __attribute__((ext_vector_type(8))) short bh8;   // 8 x bf16 (4 VGPRs)
typedef __attribute__((ext_vector_type(4))) float f4x;   // MFMA f32 accumulator

#define ALOAD(p)     __hip_atomic_load((p), __ATOMIC_RELAXED, __HIP_MEMORY_SCOPE_AGENT)
#define ASTORE(p, v) __hip_atomic_store((p), (v), __ATOMIC_RELAXED, __HIP_MEMORY_SCOPE_AGENT)

// ---------------- mask dtype detection ----------------
__global__ void detect_mask_k(const unsigned* __restrict__ m, unsigned* __restrict__ flag) {
    int t = threadIdx.x;                 // 64 threads
    unsigned bad = 0;
#pragma unroll
    for (int i = 0; i < 4; ++i) { unsigned v = m[t * 4 + i]; bad |= (v > 1u); }
    unsigned long long bb = __ballot(bad != 0u);
    if (t == 0) flag[0] = (bb != 0ull) ? 1u : 0u;
}

// ---------------- blend: hdn = where(emo & s>=1, (emb+hid)*0.5, hid), bf16 out ----------------
__global__ void blend_k(const int* __restrict__ x, const void* __restrict__ mask,
                        const float* __restrict__ hid, const float* __restrict__ emb,
                        const unsigned* __restrict__ flag, unsigned short* __restrict__ hdn) {
    int row = blockIdx.x;                // b*512 + s
    int t = threadIdx.x;                 // 192 threads, 4 floats each (768)
    if (t >= 192) return;
    int s = row & 511;
    int tok = x[row];
    bool emo;
    if (flag[0]) emo = ((const unsigned char*)mask)[tok] != 0;
    else         emo = ((const int*)mask)[tok] != 0;
    bool bl = emo && (s >= 1);
    float4 v = *(const float4*)(hid + (size_t)row * E_ + t * 4);
    if (bl) {
        float4 e = *(const float4*)(emb + (size_t)tok * E_ + t * 4);
        v.x = (v.x + e.x) * 0.5f; v.y = (v.y + e.y) * 0.5f;
        v.z = (v.z + e.z) * 0.5f; v.w = (v.w + e.w) * 0.5f;
    }
    ushort4 o; o.x = f2b(v.x); o.y = f2b(v.y); o.z = f2b(v.z); o.w = f2b(v.w);
    *(ushort4*)(hdn + (size_t)row * E_ + t * 4) = o;
}

// ---------------- f32 -> bf16 weight conversion ----------------
__global__ void cvt_k(const float* __restrict__ in, unsigned short* __restrict__ o, int n) {
    int i = (blockIdx.x * blockDim.x + threadIdx.x) * 4;
    if (i >= n) return;
    float4 v = *(const float4*)(in + i);
    ushort4 u; u.x = f2b(v.x); u.y = f2b(v.y); u.z = f2b(v.z); u.w = f2b(v.w);
    *(ushort4*)(o + i) = u;
}

// ---------------- bias sum: o = a + b ----------------
__global__ void bsum_k(const float* __restrict__ a, const float* __restrict__ b,
                       float* __restrict__ o) {
    int i = blockIdx.x * blockDim.x + threadIdx.x;
    o[i] = a[i] + b[i];
}

// ---------------- bf16 MFMA GEMM:  C[M,N] = A[M,K] @ B[N,K]^T ----------------
// PERM=1: permute output column n = gate*1024 + w*8 + uu -> n' = w*32 + gate*8 + uu
template <int AF32, int PERM>
__global__ __launch_bounds__(256) void gemm_k(const void* __restrict__ Ap,
        const unsigned short* __restrict__ Bp, unsigned short* __restrict__ Cp,
        int K, int Nreal, int ldc, const float* __restrict__ bias, int act) {
    __shared__ char smA[16384];
    __shared__ char smB[16384];
    const int tid = threadIdx.x, l = tid & 63, w = tid >> 6;
    const int m0 = blockIdx.x * 128, n0 = blockIdx.y * 128;
    const int wr = (w >> 1) * 64, wc = (w & 1) * 64;
    f4x acc[4][4] = {};
    for (int k0 = 0; k0 < K; k0 += 64) {
#pragma unroll
        for (int it = 0; it < 4; ++it) {
            int idx = it * 256 + tid;            // 0..1023 : 128 rows x 8 x 16B
            int row = idx >> 3, c16 = idx & 7;
            int sof = (row * 128 + c16 * 16) ^ ((row & 7) << 4);
            bh8 va;
            if (AF32) {
                const float* ap = (const float*)Ap + (size_t)(m0 + row) * K + k0 + c16 * 8;
                float4 f0 = *(const float4*)ap;
                float4 f1 = *(const float4*)(ap + 4);
                va[0] = (short)f2b(f0.x); va[1] = (short)f2b(f0.y);
                va[2] = (short)f2b(f0.z); va[3] = (short)f2b(f0.w);
                va[4] = (short)f2b(f1.x); va[5] = (short)f2b(f1.y);
                va[6] = (short)f2b(f1.z); va[7] = (short)f2b(f1.w);
            } else {
                va = *(const bh8*)((const unsigned short*)Ap + (size_t)(m0 + row) * K + k0 + c16 * 8);
            }
            *(bh8*)(smA + sof) = va;
            int nr = n0 + row;
            bh8 vb = {0, 0, 0, 0, 0, 0, 0, 0};
            if (nr < Nreal) vb = *(const bh8*)(Bp + (size_t)nr * K + k0 + c16 * 8);
            *(bh8*)(smB + sof) = vb;
        }
        __syncthreads();
#pragma unroll
        for (int kk = 0; kk < 2; ++kk) {
            bh8 af[4], bf8[4];
#pragma unroll
            for (int f = 0; f < 4; ++f) {
                int ra = wr + f * 16 + (l & 15);
                af[f] = *(const bh8*)(smA + ((ra * 128 + kk * 64 + ((l >> 4) << 4)) ^ ((ra & 7) << 4)));
                int rb = wc + f * 16 + (l & 15);
                bf8[f] = *(const bh8*)(smB + ((rb * 128 + kk * 64 + ((l >> 4) << 4)) ^ ((rb & 7) << 4)));
            }
#pragma unroll
            for (int fi = 0; fi < 4; ++fi)
#pragma unroll
                for (int fj = 0; fj < 4; ++fj)
                    acc[fi][fj] = __builtin_amdgcn_mfma_f32_16x16x32_bf16(af[fi], bf8[fj], acc[fi][fj], 0, 0, 0);
        }
        __syncthreads();
    }
    // epilogue: C/D layout: col = lane&15, row = (lane>>4)*4 + reg
#pragma unroll
    for (int fi = 0; fi < 4; ++fi) {
        int rb2 = wr + fi * 16 + ((l >> 4) << 2);
#pragma unroll
        for (int fj = 0; fj < 4; ++fj) {
            int cc = n0 + wc + fj * 16 + (l & 15);
            if (cc < Nreal) {
                float bv = bias ? bias[cc] : 0.f;
                int cw = cc;
                if (PERM) {
                    int gate = cc >> 10, rem = cc & 1023;
                    cw = (rem >> 3) * 32 + gate * 8 + (cc & 7);
                }
#pragma unroll
                for (int i = 0; i < 4; ++i) {
                    float xv = acc[fi][fj][i] + bv;
                    if (act) xv = tanhf(xv);
                    Cp[(size_t)(m0 + rb2 + i) * ldc + cw] = f2b(xv);
                }
            }
        }
    }
}

// ---------------- poll: wave of 64 lanes checks 256 sub-slots (stride 16B) >= need ----------------
__device__ __forceinline__ void pollq(const unsigned* __restrict__ slots, int base,
                                      unsigned need, int l) {
    for (;;) {
        unsigned v0 = ALOAD(&slots[(base + l) * 4]);
        unsigned v1 = ALOAD(&slots[(base + 64 + l) * 4]);
        unsigned v2 = ALOAD(&slots[(base + 128 + l) * 4]);
        unsigned v3 = ALOAD(&slots[(base + 192 + l) * 4]);
        unsigned m0 = v0 < v1 ? v0 : v1;
        unsigned m1 = v2 < v3 ? v2 : v3;
        unsigned mn = m0 < m1 ? m0 : m1;
        if (__all(mn >= need)) break;
        __builtin_amdgcn_s_sleep(1);
    }
}

// ---------------- per-wave 16x16 full-K gate GEMM step ----------------
// rowb ALREADY includes the per-lane k-group offset (kq*16) -- do not re-add.
__device__ __forceinline__ void kloop(const char* __restrict__ ab, const char* __restrict__ wb,
                                      int rowb, int xorv, f4x& acc, f4x& acc2) {
#pragma unroll 8
    for (int kc = 0; kc < 32; kc += 2) {
        bh8 a0 = *(const bh8*)(ab + kc * 64);
        bh8 b0 = *(const bh8*)(wb + ((rowb + kc * 64) ^ xorv));
        acc = __builtin_amdgcn_mfma_f32_16x16x32_bf16(a0, b0, acc, 0, 0, 0);
        bh8 a1 = *(const bh8*)(ab + kc * 64 + 64);
        bh8 b1 = *(const bh8*)(wb + ((rowb + (kc + 1) * 64) ^ xorv));
        acc2 = __builtin_amdgcn_mfma_f32_16x16x32_bf16(a1, b1, acc2, 0, 0, 0);
    }
}

// ---------------- fused 2-layer persistent LSTM recurrence, v2 ----------------
// 256 WGs x 256 thr; WGs 0..127 layer 0, 128..255 layer 1; WG owns 8 hidden units
// (32 gate rows). Wave split 2x2: wave = 16 batches x 16 gate rows, FULL K (no
// cross-wave reduction). Gates init from prefetched G regs (bias folded in GEMM).
// Cell on waves 0/1 (i,f in-wave via shfl_xor 8; g,o via 2KB LDS from waves 2/3).
// Sync: per-wave sub-slot monotonic stores, wave-0-only polling, fresh h buffer
// per step (plain cached reads coherent), relaxed sc1 stores, no fences.
__global__ __launch_bounds__(256, 1) void recur3_k(
        const unsigned short* __restrict__ G,      // [16384][4096] permuted cols, bias0 folded
        const unsigned short* __restrict__ Whh0,
        const unsigned short* __restrict__ Wih1,
        const unsigned short* __restrict__ Whh1,
        const float* __restrict__ bsum1,
        float* __restrict__ out2,
        unsigned* __restrict__ h0b, unsigned* __restrict__ h1b,
        unsigned* __restrict__ slots) {
    __shared__ __align__(16) char w_lds[131072];   // L0: Whh0 | (unused) ; L1: Wih1 | Whh1
    __shared__ float gx[2][2][16][17];             // [dbuf][Mhalf][batch][row16+pad]
    const int tid = threadIdx.x, l = tid & 63, wv = tid >> 6;
    const int wg = blockIdx.x, lay = wg >> 7, w = wg & 127;
    const int n = l & 15, kq = l >> 4;
    const int mb = (wv & 1) << 4;                  // wave batch base
    const int nb = (wv >> 1) << 4;                 // wave gate-row base
    const int half = wv & 1;
    const int xorv = (n & 7) << 4;
    const int rowb = (nb + n) * 2048 + kq * 16;    // weight LDS row + k-group base (pre-XOR)

    // ---- load weight slices (row r = gate*8+uu; XOR-swizzled rows of 2KB) ----
#pragma unroll
    for (int it = 0; it < 16; ++it) {
        int idx = it * 256 + tid;                  // 32 rows x 128 chunks of 16B
        int r = idx >> 7, c16 = idx & 127;
        int Rg = (r >> 3) * 1024 + w * 8 + (r & 7);
        int dst = (r * 2048 + c16 * 16) ^ ((r & 7) << 4);
        if (lay == 0) {
            *(bh8*)(w_lds + dst) = *(const bh8*)(Whh0 + (size_t)Rg * 1024 + c16 * 8);
        } else {
            *(bh8*)(w_lds + dst) = *(const bh8*)(Wih1 + (size_t)Rg * 1024 + c16 * 8);
            *(bh8*)(w_lds + 65536 + dst) = *(const bh8*)(Whh1 + (size_t)Rg * 1024 + c16 * 8);
        }
    }
    {   // zero own slice of h[0]
        unsigned* hb = lay ? h1b : h0b;
        if (tid < 128) ASTORE(&hb[(tid >> 2) * 512 + w * 4 + (tid & 3)], 0u);
    }
    const float bias_n = lay ? bsum1[((nb + n) >> 3) * 1024 + w * 8 + ((nb + n) & 7)] : 0.f;
    f4x cS = {0.f, 0.f, 0.f, 0.f};
    __syncthreads();                               // each wave drains vmcnt before barrier
    if (tid == 0) {
        ASTORE(&slots[(lay * 256 + 2 * w) * 4], 1u);
        ASTORE(&slots[(lay * 256 + 2 * w + 1) * 4], 1u);
    }
    const int slb = lay * 256;

    unsigned short g4[4];
    if (lay == 0) {                                // preload G(s=0)
#pragma unroll
        for (int i = 0; i < 4; ++i)
            g4[i] = G[(size_t)(mb + kq * 4 + i) * 512 * G4_ + (size_t)w * 32 + nb + n];
    }

    for (int s = 0; s < S_; ++s) {
        f4x acc, acc2 = {0.f, 0.f, 0.f, 0.f};
        if (lay == 0) {
            if (wv == 0) pollq(slots, 0, (unsigned)(s + 1), l);
            __syncthreads();
            // prefetch G(s+1) (lands under the MFMA phase)
            unsigned short g4n[4];
            {
                int sn = (s + 1 < S_) ? s + 1 : s;
#pragma unroll
                for (int i = 0; i < 4; ++i)
                    g4n[i] = G[((size_t)(mb + kq * 4 + i) * 512 + sn) * G4_ + (size_t)w * 32 + nb + n];
            }
#pragma unroll
            for (int i = 0; i < 4; ++i) acc[i] = b2f(g4[i]);
            const char* hp = (const char*)h0b + (size_t)s * 65536;
            kloop(hp + (mb + n) * 2048 + kq * 16, w_lds, rowb, xorv, acc, acc2);
#pragma unroll
            for (int i = 0; i < 4; ++i) g4[i] = g4n[i];
        } else {
            // phase A: Wih1 @ out1[s] = h0[s+1]  (independent of own chain)
            if (wv == 0) pollq(slots, 0, (unsigned)(s + 2), l);
            __syncthreads();
#pragma unroll
            for (int i = 0; i < 4; ++i) acc[i] = bias_n;
            const char* hpA = (const char*)h0b + (size_t)(s + 1) * 65536;
            kloop(hpA + (mb + n) * 2048 + kq * 16, w_lds, rowb, xorv, acc, acc2);
            // phase B: Whh1 @ h1[s]  (the serial chain)
            if (wv == 0) pollq(slots, 256, (unsigned)(s + 1), l);
            __syncthreads();
            const char* hpB = (const char*)h1b + (size_t)s * 65536;
            kloop(hpB + (mb + n) * 2048 + kq * 16, w_lds + 65536, rowb, xorv, acc, acc2);
        }
        f4x at = acc + acc2;
        const int p = s & 1;
        if (wv >= 2) {                             // export g,o tiles (rows 16..31)
#pragma unroll
            for (int i = 0; i < 4; ++i) gx[p][half][kq * 4 + i][n] = at[i];
        }
        __syncthreads();
        if (wv < 2) {                              // cell on waves 0/1
            f4x ap;
#pragma unroll
            for (int i = 0; i < 4; ++i) ap[i] = __shfl_xor(at[i], 8);
            unsigned huw[4] = {0, 0, 0, 0};
            float hvf[4] = {0.f, 0.f, 0.f, 0.f};
            if (n < 8) {
#pragma unroll
                for (int i = 0; i < 4; ++i) {
                    int bl = kq * 4 + i;
                    float gi = at[i], gf = ap[i];
                    float gg = gx[p][half][bl][n];
                    float go = gx[p][half][bl][8 + n];
                    float si = 1.f / (1.f + __expf(-gi));
                    float sf = 1.f / (1.f + __expf(-gf));
                    float so = 1.f / (1.f + __expf(-go));
                    float c = sf * cS[i] + si * tanhf(gg);
                    float hv = so * tanhf(c);
                    cS[i] = c; hvf[i] = hv; huw[i] = f2b(hv);
                }
            }
            unsigned* hn = (lay ? h1b : h0b) + (size_t)(s + 1) * 16384;
#pragma unroll
            for (int i = 0; i < 4; ++i) {
                unsigned pu = __shfl_xor(huw[i], 1);
                if (n < 8 && !(n & 1))
                    ASTORE(&hn[(mb + kq * 4 + i) * 512 + w * 4 + (n >> 1)], huw[i] | (pu << 16));
            }
            asm volatile("s_waitcnt vmcnt(0)" ::: "memory");
            if (l == 0) ASTORE(&slots[(slb + 2 * w + wv) * 4], (unsigned)(s + 2));
            if (lay == 1 && n < 8) {               // fp32 out2 (off the chain, after publish)
#pragma unroll
                for (int i = 0; i < 4; ++i)
                    out2[((size_t)(mb + kq * 4 + i) * 512 + s) * 1024 + w * 8 + n] = hvf[i];
            }
        }
    }
}

// ---------------- attention score:  sc[row] = sum_r a1[row,r]*W2[r] ----------------
__global__ void score_k(const unsigned short* __restrict__ a1, const float* __restrict__ W2,
                        float* __restrict__ sc) {
    int r = blockIdx.x * blockDim.x + threadIdx.x;   // 0..16383
    const unsigned short* p = a1 + (size_t)r * 104;
    float s = 0.f;
#pragma unroll
    for (int i = 0; i < 100; ++i) s += b2f(p[i]) * W2[i];
    sc[r] = s;
}

// ---------------- per-batch: softmax over S -> w ; sent = sum_s w*out2 ; logits ----------------
__global__ __launch_bounds__(256) void attn_k(const float* __restrict__ sc,
        const float* __restrict__ out2, const float* __restrict__ Wf,
        const float* __restrict__ bf, float* __restrict__ out) {
    int b = blockIdx.x, t = threadIdx.x;
    __shared__ float p[512];
    __shared__ float red[256];
    __shared__ float sent[1024];
    float s0 = sc[b * 512 + t], s1 = sc[b * 512 + 256 + t];
    red[t] = fmaxf(s0, s1);
    __syncthreads();
    for (int o = 128; o > 0; o >>= 1) { if (t < o) red[t] = fmaxf(red[t], red[t + o]); __syncthreads(); }
    float M = red[0];
    __syncthreads();
    float e0 = __expf(s0 - M), e1 = __expf(s1 - M);
    red[t] = e0 + e1;
    __syncthreads();
    for (int o = 128; o > 0; o >>= 1) { if (t < o) red[t] += red[t + o]; __syncthreads(); }
    float inv = 1.f / red[0];
    float w0 = e0 * inv, w1 = e1 * inv;
    p[t] = w0; p[t + 256] = w1;
    out[160 + b * 512 + t] = w0;
    out[160 + b * 512 + 256 + t] = w1;
    __syncthreads();
    float4 acc = {0.f, 0.f, 0.f, 0.f};
    for (int s = 0; s < 512; ++s) {
        float ws = p[s];
        float4 v = *(const float4*)(out2 + ((size_t)b * 512 + s) * H_ + t * 4);
        acc.x += ws * v.x; acc.y += ws * v.y; acc.z += ws * v.z; acc.w += ws * v.w;
    }
    *(float4*)(sent + t * 4) = acc;
    __syncthreads();
    int wv = t >> 6, ln = t & 63;
    for (int n = wv; n < 5; n += 4) {
        float prt = 0.f;
        for (int k = ln; k < 1024; k += 64) prt += sent[k] * Wf[n * 1024 + k];
#pragma unroll
        for (int o = 32; o > 0; o >>= 1) prt += __shfl_down(prt, o);
        if (ln == 0) out[b * 5 + n] = prt + bf[n];
    }
}

// ---------------- workspace layout (bytes); total kept within proven 297,533,440 ----------------
#define OFF_FLAG  ((size_t)0)
#define OFF_WH0   ((size_t)4096)                           // 8,388,608
#define OFF_W1I   (OFF_WH0 + (size_t)G4_ * H_ * 2)         // 8,392,704
#define OFF_WH1   (OFF_W1I + (size_t)G4_ * H_ * 2)         // 16,781,312
#define OFF_W1A   (OFF_WH1 + (size_t)G4_ * H_ * 2)         // 25,169,920 : 204,800
#define OFF_BS0   (OFF_W1A + (size_t)204800)               // 25,374,720 : 16,384
#define OFF_BS1   (OFF_BS0 + (size_t)16384)                // 25,391,104 : 16,384
#define OFF_SLOT  (OFF_BS1 + (size_t)16384)                // 25,407,488 : 8,192 (512 slots x16B)
#define OFF_G     ((size_t)25432064)                       // bf16 [16384][4096] 134MB
#define OFF_OUT2  (OFF_G + (size_t)BS_ * G4_ * 2)          // 159,649,792 : 67,108,864
#define OFF_HDN   OFF_OUT2                                 // hdn (25.2MB) overlays out2 (dead before recur)
#define OFF_W0    (OFF_HDN + (size_t)BS_ * E_ * 2)         // w0b (6.3MB) also inside out2
#define OFF_A1    (OFF_OUT2 + (size_t)BS_ * H_ * 4)        // 226,758,656 : 3,407,872 (ldc=104)
#define OFF_SC    (OFF_A1 + (size_t)BS_ * 104 * 2)         // 230,166,528 : 65,536
#define OFF_H0    ((size_t)230293504)                      // 64KB-aligned : 513*65,536
#define OFF_H1    (OFF_H0 + (size_t)513 * 65536)           // 263,913,472 : 513*65,536 -> 297,533,440

extern "C" void kernel_launch(void* const* d_in, const int* in_sizes, int n_in,
                              void* d_out, int out_size, void* d_ws, size_t ws_size,
                              hipStream_t stream) {
    const int*   x    = (const int*)d_in[0];
    const void*  mask = d_in[1];
    const float* hid  = (const float*)d_in[2];
    const float* emb  = (const float*)d_in[3];
    const float* Wih0 = (const float*)d_in[4];
    const float* Whh0 = (const float*)d_in[5];
    const float* bih0 = (const float*)d_in[6];
    const float* bhh0 = (const float*)d_in[7];
    const float* Wih1 = (const float*)d_in[8];
    const float* Whh1 = (const float*)d_in[9];
    const float* bih1 = (const float*)d_in[10];
    const float* bhh1 = (const float*)d_in[11];
    const float* W1   = (const float*)d_in[12];
    const float* b1   = (const float*)d_in[13];
    const float* W2   = (const float*)d_in[14];
    const float* Wf   = (const float*)d_in[16];
    const float* bfp  = (const float*)d_in[17];
    float* out = (float*)d_out;
    char* ws = (char*)d_ws;

    unsigned*       flag  = (unsigned*)(ws + OFF_FLAG);
    unsigned short* wh0b  = (unsigned short*)(ws + OFF_WH0);
    unsigned short* w1ib  = (unsigned short*)(ws + OFF_W1I);
    unsigned short* wh1b  = (unsigned short*)(ws + OFF_WH1);
    unsigned short* w1ab  = (unsigned short*)(ws + OFF_W1A);
    float*          bs0   = (float*)(ws + OFF_BS0);
    float*          bs1   = (float*)(ws + OFF_BS1);
    unsigned*       slots = (unsigned*)(ws + OFF_SLOT);
    unsigned short* Gb    = (unsigned short*)(ws + OFF_G);
    float*          out2f = (float*)(ws + OFF_OUT2);
    unsigned short* hdn   = (unsigned short*)(ws + OFF_HDN);
    unsigned short* w0b   = (unsigned short*)(ws + OFF_W0);
    unsigned short* a1b   = (unsigned short*)(ws + OFF_A1);
    float*          scb   = (float*)(ws + OFF_SC);
    unsigned*       h0b   = (unsigned*)(ws + OFF_H0);
    unsigned*       h1b   = (unsigned*)(ws + OFF_H1);

    hipMemsetAsync(ws, 0, 4096, stream);                    // flag
    hipMemsetAsync(ws + OFF_SLOT, 0, 8192, stream);         // slots

    detect_mask_k<<<1, 64, 0, stream>>>((const unsigned*)mask, flag);
    blend_k<<<BS_, 192, 0, stream>>>(x, mask, hid, emb, flag, hdn);
    cvt_k<<<3072, 256, 0, stream>>>(Wih0, w0b, G4_ * E_);
    cvt_k<<<4096, 256, 0, stream>>>(Whh0, wh0b, G4_ * H_);
    cvt_k<<<4096, 256, 0, stream>>>(Wih1, w1ib, G4_ * H_);
    cvt_k<<<4096, 256, 0, stream>>>(Whh1, wh1b, G4_ * H_);
    cvt_k<<<100, 256, 0, stream>>>(W1, w1ab, 100 * H_);
    bsum_k<<<16, 256, 0, stream>>>(bih0, bhh0, bs0);
    bsum_k<<<16, 256, 0, stream>>>(bih1, bhh1, bs1);

    // G = hdn @ Wih0^T + (bih0+bhh0), permuted column layout
    gemm_k<0, 1><<<dim3(BS_ / 128, G4_ / 128), 256, 0, stream>>>(hdn, w0b, Gb, E_, G4_, G4_, bs0, 0);

    {   // fused 2-layer recurrence
        const unsigned short* a0 = Gb;
        const unsigned short* a1p = wh0b;
        const unsigned short* a2 = w1ib;
        const unsigned short* a3 = wh1b;
        const float* a4 = bs1;
        float* a5 = out2f;
        unsigned* a6 = h0b; unsigned* a7 = h1b; unsigned* a8 = slots;
        void* args[] = {&a0, &a1p, &a2, &a3, &a4, &a5, &a6, &a7, &a8};
        hipLaunchCooperativeKernel((const void*)recur3_k, dim3(256), dim3(256), args, 0, stream);
    }

    // a1 = tanh(out2 @ W1^T + b1)   N=100, ldc=104
    gemm_k<1, 0><<<dim3(BS_ / 128, 1), 256, 0, stream>>>(out2f, w1ab, a1b, H_, 100, 104, b1, 1);
    score_k<<<BS_ / 256, 256, 0, stream>>>(a1b, W2, scb);
    attn_k<<<B_, 256, 0, stream>>>(scb, out2f, Wf, bfp, out);

    (void)in_sizes; (void)n_in; (void)out_size; (void)ws_size;
}